// Round 1
// baseline (872.756 us; speedup 1.0000x reference)
//
#include <hip/hip_runtime.h>

#define NN 50000
#define EE 640000
#define ET (EE + NN)
#define GG 512
#define CAP 128

// ---------- precompute: w_e[k][l*4+h] = sum_c lin_e_w[l][k][h*32+c]*att_e[l][h][c]
__global__ __launch_bounds__(256) void k_we(const float* __restrict__ lin_e_w,
                                            const float* __restrict__ att_e,
                                            float* __restrict__ w_e) {
    int idx = blockIdx.x * 256 + threadIdx.x;
    if (idx >= 128 * 16) return;
    int k = idx >> 4, lh = idx & 15, l = lh >> 2, h = lh & 3;
    const float* wrow = lin_e_w + l * 16384 + k * 128 + h * 32;
    const float* arow = att_e + l * 128 + h * 32;
    float acc = 0.f;
#pragma unroll
    for (int c = 0; c < 32; c++) acc += wrow[c] * arow[c];
    w_e[k * 16 + lh] = acc;
}

// Mt[lh][r] : r<3 -> enc_edge_w row r composed with w_e col lh ; r==3 -> bias row
__global__ __launch_bounds__(64) void k_me(const float* __restrict__ encW,
                                           const float* __restrict__ encB,
                                           const float* __restrict__ w_e,
                                           float* __restrict__ Mt) {
    int idx = threadIdx.x;
    if (idx >= 64) return;
    int lh = idx >> 2, r = idx & 3;
    float acc = 0.f;
    for (int k = 0; k < 128; k++) {
        float a = (r < 3) ? encW[r * 128 + k] : encB[k];
        acc += a * w_e[k * 16 + lh];
    }
    Mt[lh * 4 + r] = acc;
}

// node encoder: h = x @ enc_node_w + b
__global__ __launch_bounds__(256) void k_enc(const float* __restrict__ x,
                                             const float* __restrict__ W,
                                             const float* __restrict__ b,
                                             float* __restrict__ h) {
    int i = blockIdx.x * 256 + threadIdx.x;
    if (i >= NN * 128) return;
    int n = i >> 7, c = i & 127;
    float acc = b[c];
    const float* xr = x + n * 8;
#pragma unroll
    for (int f = 0; f < 8; f++) acc += xr[f] * W[f * 128 + c];
    h[i] = acc;
}

__global__ __launch_bounds__(256) void k_deg(const int* __restrict__ dst, int* __restrict__ deg) {
    int e = blockIdx.x * 256 + threadIdx.x;
    if (e < EE) atomicAdd(&deg[dst[e]], 1);
}

// exclusive row_ptr over deg+1 (self-loop included), single 1024-thread block scan
__global__ __launch_bounds__(1024) void k_scan(const int* __restrict__ deg, int* __restrict__ rp) {
    __shared__ int wsum[16];
    __shared__ int carry_sh;
    int tid = threadIdx.x, lane = tid & 63, wid = tid >> 6;
    if (tid == 0) { carry_sh = 0; rp[0] = 0; }
    __syncthreads();
    for (int base = 0; base < NN; base += 1024) {
        int i = base + tid;
        int v = (i < NN) ? deg[i] + 1 : 0;
        int xv = v;
        for (int off = 1; off < 64; off <<= 1) {
            int t = __shfl_up(xv, off);
            if (lane >= off) xv += t;
        }
        if (lane == 63) wsum[wid] = xv;
        __syncthreads();
        if (wid == 0) {
            int s = (lane < 16) ? wsum[lane] : 0;
            for (int off = 1; off < 16; off <<= 1) {
                int t = __shfl_up(s, off);
                if (lane >= off) s += t;
            }
            if (lane < 16) wsum[lane] = s;
        }
        __syncthreads();
        int incl = carry_sh + (wid > 0 ? wsum[wid - 1] : 0) + xv;
        if (i < NN) rp[i + 1] = incl;
        __syncthreads();
        if (tid == 1023) carry_sh += wsum[15];
        __syncthreads();
    }
}

// scatter edges into CSR slots; attr4 = (a0,a1,a2,1) so bias rides the w-component
__global__ __launch_bounds__(256) void k_fill(const int* __restrict__ src, const int* __restrict__ dst,
                                              const float* __restrict__ edge_attr,
                                              const int* __restrict__ rp, int* __restrict__ fill,
                                              int* __restrict__ srcs, float* __restrict__ attr4) {
    int e = blockIdx.x * 256 + threadIdx.x;
    if (e >= EE) return;
    int d = dst[e];
    int ofs = atomicAdd(&fill[d], 1);
    int pos = rp[d] + ofs;
    srcs[pos] = src[e];
    const float* ar = edge_attr + e * 3;
    float4 v = make_float4(ar[0], ar[1], ar[2], 1.f);
    *(float4*)(attr4 + pos * 4) = v;
}

// self-loop entry at the last CSR slot of each node: mean of incoming attr4
// (w-component: deg/max(deg,1) -> 1, or 0 for isolated nodes == reference's zero loop_ea)
__global__ __launch_bounds__(256) void k_selfloop(const int* __restrict__ rp, int* __restrict__ srcs,
                                                  float* __restrict__ attr4) {
    int t = blockIdx.x * 256 + threadIdx.x;
    if (t >= NN * 4) return;
    int n = t >> 2, j = t & 3;
    int b = rp[n], en = rp[n + 1];
    int d = en - b - 1;
    float s = 0.f;
    for (int k = 0; k < d; k++) s += attr4[(b + k) * 4 + j];
    attr4[(en - 1) * 4 + j] = s / fmaxf((float)d, 1.f);
    if (j == 0) srcs[en - 1] = n;
}

// xp = h @ lin_w  (50000x128 @ 128x128) + fused s/d attention-dot epilogue
__global__ __launch_bounds__(256) void k_gemm(const float* __restrict__ hmat, const float* __restrict__ W,
                                              const float* __restrict__ a_src, const float* __restrict__ a_dst,
                                              float* __restrict__ xp, float* __restrict__ s_arr,
                                              float* __restrict__ d_arr) {
    __shared__ __align__(16) float Wl[64 * 128];   // 32 KB (k-chunked)
    __shared__ __align__(16) float A[32 * 132];    // 16.5 KB, +4 pad breaks bank aliasing
    int tid = threadIdx.x;
    int rowBase = blockIdx.x * 32;
    for (int idx = tid; idx < 1024; idx += 256) {
        int r = idx >> 5, c4 = (idx & 31) << 2;
        int gr = rowBase + r;
        float4 v = make_float4(0, 0, 0, 0);
        if (gr < NN) v = *(const float4*)(hmat + gr * 128 + c4);
        *(float4*)(&A[r * 132 + c4]) = v;
    }
    float4 acc[4];
    acc[0] = acc[1] = acc[2] = acc[3] = make_float4(0, 0, 0, 0);
    int rl = tid >> 5, c0 = (tid & 31) << 2;
    for (int kc = 0; kc < 2; kc++) {
        __syncthreads();
        for (int idx = tid; idx < 2048; idx += 256) {
            int r = idx >> 5, c4 = (idx & 31) << 2;
            *(float4*)(&Wl[r * 128 + c4]) = *(const float4*)(W + (kc * 64 + r) * 128 + c4);
        }
        __syncthreads();
        for (int kk = 0; kk < 64; kk += 4) {
            int kg = kc * 64 + kk;
            float4 a0 = *(float4*)(&A[rl * 132 + kg]);
            float4 a1 = *(float4*)(&A[(rl + 8) * 132 + kg]);
            float4 a2 = *(float4*)(&A[(rl + 16) * 132 + kg]);
            float4 a3 = *(float4*)(&A[(rl + 24) * 132 + kg]);
#pragma unroll
            for (int u = 0; u < 4; u++) {
                float4 w4 = *(float4*)(&Wl[(kk + u) * 128 + c0]);
                float b0 = (&a0.x)[u], b1 = (&a1.x)[u], b2 = (&a2.x)[u], b3 = (&a3.x)[u];
                acc[0].x += b0 * w4.x; acc[0].y += b0 * w4.y; acc[0].z += b0 * w4.z; acc[0].w += b0 * w4.w;
                acc[1].x += b1 * w4.x; acc[1].y += b1 * w4.y; acc[1].z += b1 * w4.z; acc[1].w += b1 * w4.w;
                acc[2].x += b2 * w4.x; acc[2].y += b2 * w4.y; acc[2].z += b2 * w4.z; acc[2].w += b2 * w4.w;
                acc[3].x += b3 * w4.x; acc[3].y += b3 * w4.y; acc[3].z += b3 * w4.z; acc[3].w += b3 * w4.w;
            }
        }
    }
    int hh = c0 >> 5, o = c0 & 31;
    float4 as = *(const float4*)(a_src + hh * 32 + o);
    float4 ad = *(const float4*)(a_dst + hh * 32 + o);
#pragma unroll
    for (int i = 0; i < 4; i++) {
        int gr = rowBase + rl + i * 8;
        if (gr < NN) *(float4*)(xp + gr * 128 + c0) = acc[i];
        float sp = acc[i].x * as.x + acc[i].y * as.y + acc[i].z * as.z + acc[i].w * as.w;
        float dp = acc[i].x * ad.x + acc[i].y * ad.y + acc[i].z * ad.z + acc[i].w * ad.w;
#pragma unroll
        for (int off = 1; off < 8; off <<= 1) { sp += __shfl_xor(sp, off); dp += __shfl_xor(dp, off); }
        if (((tid & 7) == 0) && gr < NN) { s_arr[gr * 4 + hh] = sp; d_arr[gr * 4 + hh] = dp; }
    }
}

// fused segment softmax + message aggregation: one wave per destination node
__global__ __launch_bounds__(256) void k_edge(const int* __restrict__ rp, const int* __restrict__ srcs,
                                              const float* __restrict__ attr4, const float* __restrict__ Mt,
                                              const float* __restrict__ s_arr, const float* __restrict__ d_arr,
                                              const float* __restrict__ xp, float* __restrict__ out, int layer) {
    __shared__ float shw[4][CAP * 4];
    __shared__ int shs[4][CAP];
    int wid = threadIdx.x >> 6, lane = threadIdx.x & 63;
    int node = blockIdx.x * 4 + wid;
    if (node >= NN) return;
    int start = rp[node], end = rp[node + 1];
    int k = end - start;
    float4 d4 = *(const float4*)(d_arr + node * 4);
    float4 mt0 = *(const float4*)(Mt + (layer * 4 + 0) * 4);
    float4 mt1 = *(const float4*)(Mt + (layer * 4 + 1) * 4);
    float4 mt2 = *(const float4*)(Mt + (layer * 4 + 2) * 4);
    float4 mt3 = *(const float4*)(Mt + (layer * 4 + 3) * 4);
    float m0 = -1e30f, m1 = -1e30f, m2 = -1e30f, m3 = -1e30f;
    for (int base = 0; base < k; base += 64) {
        int j = base + lane;
        if (j < k) {
            int pos = start + j;
            int sv = srcs[pos];
            float4 s4 = *(const float4*)(s_arr + sv * 4);
            float4 a4 = *(const float4*)(attr4 + pos * 4);
            float e0 = a4.x * mt0.x + a4.y * mt0.y + a4.z * mt0.z + a4.w * mt0.w;
            float e1 = a4.x * mt1.x + a4.y * mt1.y + a4.z * mt1.z + a4.w * mt1.w;
            float e2 = a4.x * mt2.x + a4.y * mt2.y + a4.z * mt2.z + a4.w * mt2.w;
            float e3 = a4.x * mt3.x + a4.y * mt3.y + a4.z * mt3.z + a4.w * mt3.w;
            float al0 = s4.x + d4.x + e0; al0 = al0 > 0.f ? al0 : 0.2f * al0;
            float al1 = s4.y + d4.y + e1; al1 = al1 > 0.f ? al1 : 0.2f * al1;
            float al2 = s4.z + d4.z + e2; al2 = al2 > 0.f ? al2 : 0.2f * al2;
            float al3 = s4.w + d4.w + e3; al3 = al3 > 0.f ? al3 : 0.2f * al3;
            if (j < CAP) {
                shs[wid][j] = sv;
                float* p = &shw[wid][j * 4];
                p[0] = al0; p[1] = al1; p[2] = al2; p[3] = al3;
            }
            m0 = fmaxf(m0, al0); m1 = fmaxf(m1, al1); m2 = fmaxf(m2, al2); m3 = fmaxf(m3, al3);
        }
    }
#pragma unroll
    for (int off = 32; off; off >>= 1) {
        m0 = fmaxf(m0, __shfl_xor(m0, off));
        m1 = fmaxf(m1, __shfl_xor(m1, off));
        m2 = fmaxf(m2, __shfl_xor(m2, off));
        m3 = fmaxf(m3, __shfl_xor(m3, off));
    }
    __builtin_amdgcn_wave_barrier();
    float z0 = 0, z1 = 0, z2 = 0, z3 = 0;
    for (int base = 0; base < k; base += 64) {
        int j = base + lane;
        if (j < k) {
            float al0, al1, al2, al3;
            if (j < CAP) {
                float* p = &shw[wid][j * 4];
                al0 = p[0]; al1 = p[1]; al2 = p[2]; al3 = p[3];
            } else {  // overflow fallback (deg > CAP): recompute
                int pos = start + j;
                int sv = srcs[pos];
                float4 s4 = *(const float4*)(s_arr + sv * 4);
                float4 a4 = *(const float4*)(attr4 + pos * 4);
                float e0 = a4.x * mt0.x + a4.y * mt0.y + a4.z * mt0.z + a4.w * mt0.w;
                float e1 = a4.x * mt1.x + a4.y * mt1.y + a4.z * mt1.z + a4.w * mt1.w;
                float e2 = a4.x * mt2.x + a4.y * mt2.y + a4.z * mt2.z + a4.w * mt2.w;
                float e3 = a4.x * mt3.x + a4.y * mt3.y + a4.z * mt3.z + a4.w * mt3.w;
                al0 = s4.x + d4.x + e0; al0 = al0 > 0.f ? al0 : 0.2f * al0;
                al1 = s4.y + d4.y + e1; al1 = al1 > 0.f ? al1 : 0.2f * al1;
                al2 = s4.z + d4.z + e2; al2 = al2 > 0.f ? al2 : 0.2f * al2;
                al3 = s4.w + d4.w + e3; al3 = al3 > 0.f ? al3 : 0.2f * al3;
            }
            float w0 = __expf(al0 - m0), w1 = __expf(al1 - m1), w2 = __expf(al2 - m2), w3 = __expf(al3 - m3);
            z0 += w0; z1 += w1; z2 += w2; z3 += w3;
            if (j < CAP) {
                float* p = &shw[wid][j * 4];
                p[0] = w0; p[1] = w1; p[2] = w2; p[3] = w3;
            }
        }
    }
#pragma unroll
    for (int off = 32; off; off >>= 1) {
        z0 += __shfl_xor(z0, off); z1 += __shfl_xor(z1, off);
        z2 += __shfl_xor(z2, off); z3 += __shfl_xor(z3, off);
    }
    float zi0 = 1.f / (z0 + 1e-16f), zi1 = 1.f / (z1 + 1e-16f);
    float zi2 = 1.f / (z2 + 1e-16f), zi3 = 1.f / (z3 + 1e-16f);
    __builtin_amdgcn_wave_barrier();
    int c0 = lane * 2, hh = c0 >> 5;
    float zi = hh == 0 ? zi0 : hh == 1 ? zi1 : hh == 2 ? zi2 : zi3;
    float mh = hh == 0 ? m0 : hh == 1 ? m1 : hh == 2 ? m2 : m3;
    float dh = hh == 0 ? d4.x : hh == 1 ? d4.y : hh == 2 ? d4.z : d4.w;
    float4 mth = hh == 0 ? mt0 : hh == 1 ? mt1 : hh == 2 ? mt2 : mt3;
    float acc0 = 0.f, acc1 = 0.f;
    for (int j = 0; j < k; j++) {
        float w; int sv;
        if (j < CAP) { w = shw[wid][j * 4 + hh]; sv = shs[wid][j]; }
        else {
            int pos = start + j;
            sv = srcs[pos];
            float s = s_arr[sv * 4 + hh];
            float4 a4 = *(const float4*)(attr4 + pos * 4);
            float ev = a4.x * mth.x + a4.y * mth.y + a4.z * mth.z + a4.w * mth.w;
            float a = s + dh + ev; a = a > 0.f ? a : 0.2f * a;
            w = __expf(a - mh);
        }
        w *= zi;
        float2 xv = *(const float2*)(xp + sv * 128 + c0);
        acc0 += w * xv.x; acc1 += w * xv.y;
    }
    *(float2*)(out + node * 128 + c0) = make_float2(acc0, acc1);
}

// BN stats: per-channel sum + sumsq  (gat_bias dropped: constant per channel, BN cancels it)
__global__ __launch_bounds__(256) void k_bnstats(const float* __restrict__ x, float* __restrict__ sums) {
    int tid = threadIdx.x;
    int c = tid & 127, half = tid >> 7;
    float s = 0.f, q = 0.f;
    for (int n = blockIdx.x * 2 + half; n < NN; n += gridDim.x * 2) {
        float v = x[n * 128 + c];
        s += v; q += v * v;
    }
    __shared__ float sh[256];
    sh[tid] = s; __syncthreads();
    if (tid < 128) atomicAdd(&sums[c], sh[tid] + sh[tid + 128]);
    __syncthreads();
    sh[tid] = q; __syncthreads();
    if (tid < 128) atomicAdd(&sums[128 + c], sh[tid] + sh[tid + 128]);
}

__global__ __launch_bounds__(256) void k_norm(const float* __restrict__ out, const float* __restrict__ sums,
                                              const float* __restrict__ gamma, const float* __restrict__ beta,
                                              float* __restrict__ h, int first) {
    int i = blockIdx.x * 256 + threadIdx.x;
    if (i >= NN * 128) return;
    int c = i & 127;
    float mu = sums[c] * (1.f / NN);
    float var = sums[128 + c] * (1.f / NN) - mu * mu;
    float iv = rsqrtf(fmaxf(var, 0.f) + 1e-5f);
    float v = (out[i] - mu) * iv * gamma[c] + beta[c];
    v = fmaxf(v, 0.f);
    h[i] = first ? v : h[i] + v;
}

__global__ __launch_bounds__(256) void k_cnt(const int* __restrict__ batch, int* __restrict__ cnt) {
    int n = blockIdx.x * 256 + threadIdx.x;
    if (n < NN) atomicAdd(&cnt[batch[n]], 1);
}

__global__ __launch_bounds__(256) void k_pool(const float* __restrict__ h, const int* __restrict__ batch,
                                              float* __restrict__ g) {
    int i = blockIdx.x * 256 + threadIdx.x;
    if (i >= NN * 128) return;
    int n = i >> 7, c = i & 127;
    atomicAdd(&g[batch[n] * 128 + c], h[i]);
}

__global__ __launch_bounds__(128) void k_fc(const float* __restrict__ g, const int* __restrict__ cnt,
                                            const float* __restrict__ w1, const float* __restrict__ b1,
                                            const float* __restrict__ w2, const float* __restrict__ b2,
                                            const float* __restrict__ w3, const float* __restrict__ b3,
                                            float* __restrict__ out) {
    __shared__ float gv[128];
    __shared__ float h1[128];
    __shared__ float h2[64];
    int gi = blockIdx.x, t = threadIdx.x;
    float c = fmaxf((float)cnt[gi], 1.f);
    gv[t] = g[gi * 128 + t] / c;
    __syncthreads();
    float acc = b1[t];
    for (int kk = 0; kk < 128; kk++) acc += gv[kk] * w1[kk * 128 + t];
    h1[t] = fmaxf(acc, 0.f);
    __syncthreads();
    if (t < 64) {
        float a2 = b2[t];
        for (int kk = 0; kk < 128; kk++) a2 += h1[kk] * w2[kk * 64 + t];
        h2[t] = fmaxf(a2, 0.f);
    }
    __syncthreads();
    if (t < 64) {
        float p = h2[t] * w3[t];
#pragma unroll
        for (int off = 32; off; off >>= 1) p += __shfl_xor(p, off);
        if (t == 0) out[gi] = p + b3[0];
    }
}

extern "C" void kernel_launch(void* const* d_in, const int* in_sizes, int n_in,
                              void* d_out, int out_size, void* d_ws, size_t ws_size,
                              hipStream_t stream) {
    const float* x            = (const float*)d_in[0];
    const float* edge_attr    = (const float*)d_in[1];
    const int*   edge_index   = (const int*)d_in[2];
    const int*   batch        = (const int*)d_in[3];
    const float* enc_node_w   = (const float*)d_in[4];
    const float* enc_node_b   = (const float*)d_in[5];
    const float* enc_edge_w   = (const float*)d_in[6];
    const float* enc_edge_b   = (const float*)d_in[7];
    const float* gat_lin_w    = (const float*)d_in[8];
    const float* gat_att_src  = (const float*)d_in[9];
    const float* gat_att_dst  = (const float*)d_in[10];
    const float* gat_lin_edge = (const float*)d_in[11];
    const float* gat_att_edge = (const float*)d_in[12];
    // d_in[13] = gat_bias: constant per channel before training-mode BN -> cancels, unused
    const float* bn_gamma     = (const float*)d_in[14];
    const float* bn_beta      = (const float*)d_in[15];
    const float* fc1_w        = (const float*)d_in[16];
    const float* fc1_b        = (const float*)d_in[17];
    const float* fc2_w        = (const float*)d_in[18];
    const float* fc2_b        = (const float*)d_in[19];
    const float* fc3_w        = (const float*)d_in[20];
    const float* fc3_b        = (const float*)d_in[21];
    float* outv = (float*)d_out;

    char* ws = (char*)d_ws;
    size_t off = 0;
    auto alloc = [&](size_t bytes) -> void* {
        void* p = ws + off;
        off = (off + bytes + 255) & ~(size_t)255;
        return p;
    };
    float* h     = (float*)alloc((size_t)NN * 128 * 4);
    float* gout  = (float*)alloc((size_t)NN * 128 * 4);
    float* xp    = (float*)alloc((size_t)NN * 128 * 4);
    float* s_arr = (float*)alloc((size_t)NN * 4 * 4);
    float* d_arr = (float*)alloc((size_t)NN * 4 * 4);
    int*   deg   = (int*)alloc((size_t)NN * 4);
    int*   fill  = (int*)alloc((size_t)NN * 4);
    int*   rp    = (int*)alloc((size_t)(NN + 1) * 4);
    int*   srcs  = (int*)alloc((size_t)ET * 4);
    float* attr4 = (float*)alloc((size_t)ET * 4 * 4);
    float* w_e   = (float*)alloc(128 * 16 * 4);
    float* Mt    = (float*)alloc(64 * 4);
    float* bns   = (float*)alloc(256 * 4);
    float* g     = (float*)alloc((size_t)GG * 128 * 4);
    int*   cnt   = (int*)alloc((size_t)GG * 4);
    (void)ws_size; (void)in_sizes; (void)n_in; (void)out_size;

    hipMemsetAsync(deg, 0, NN * 4, stream);
    hipMemsetAsync(fill, 0, NN * 4, stream);
    hipMemsetAsync(g, 0, GG * 128 * 4, stream);
    hipMemsetAsync(cnt, 0, GG * 4, stream);

    const int* srce = edge_index;
    const int* dste = edge_index + EE;

    k_we<<<8, 256, 0, stream>>>(gat_lin_edge, gat_att_edge, w_e);
    k_me<<<1, 64, 0, stream>>>(enc_edge_w, enc_edge_b, w_e, Mt);
    k_enc<<<(NN * 128 + 255) / 256, 256, 0, stream>>>(x, enc_node_w, enc_node_b, h);
    k_deg<<<(EE + 255) / 256, 256, 0, stream>>>(dste, deg);
    k_scan<<<1, 1024, 0, stream>>>(deg, rp);
    k_fill<<<(EE + 255) / 256, 256, 0, stream>>>(srce, dste, edge_attr, rp, fill, srcs, attr4);
    k_selfloop<<<(NN * 4 + 255) / 256, 256, 0, stream>>>(rp, srcs, attr4);

    for (int l = 0; l < 4; l++) {
        k_gemm<<<(NN + 31) / 32, 256, 0, stream>>>(h, gat_lin_w + l * 16384,
                                                   gat_att_src + l * 128, gat_att_dst + l * 128,
                                                   xp, s_arr, d_arr);
        k_edge<<<NN / 4, 256, 0, stream>>>(rp, srcs, attr4, Mt, s_arr, d_arr, xp, gout, l);
        hipMemsetAsync(bns, 0, 256 * 4, stream);
        k_bnstats<<<256, 256, 0, stream>>>(gout, bns);
        k_norm<<<(NN * 128 + 255) / 256, 256, 0, stream>>>(gout, bns, bn_gamma + l * 128,
                                                           bn_beta + l * 128, h, l == 0 ? 1 : 0);
    }

    k_cnt<<<(NN + 255) / 256, 256, 0, stream>>>(batch, cnt);
    k_pool<<<(NN * 128 + 255) / 256, 256, 0, stream>>>(h, batch, g);
    k_fc<<<GG, 128, 0, stream>>>(g, cnt, fc1_w, fc1_b, fc2_w, fc2_b, fc3_w, fc3_b, outv);
}

// Round 2
// 841.925 us; speedup vs baseline: 1.0366x; 1.0366x over previous
//
#include <hip/hip_runtime.h>
#include <hip/hip_bf16.h>

#define NN 50000
#define EE 640000
#define ET (EE + NN)
#define GG 512
#define CAP 128

typedef unsigned int uint;

__device__ inline float2 bf2f(uint u) {
    return make_float2(__uint_as_float(u << 16), __uint_as_float(u & 0xffff0000u));
}
__device__ inline uint packbf(float a, float b) {
    __hip_bfloat162 t;
    t.x = __float2bfloat16(a);
    t.y = __float2bfloat16(b);
    return *(uint*)&t;
}

// ---------- precompute: w_e[k][l*4+h] = sum_c lin_e_w[l][k][h*32+c]*att_e[l][h][c]
__global__ __launch_bounds__(256) void k_we(const float* __restrict__ lin_e_w,
                                            const float* __restrict__ att_e,
                                            float* __restrict__ w_e) {
    int idx = blockIdx.x * 256 + threadIdx.x;
    if (idx >= 128 * 16) return;
    int k = idx >> 4, lh = idx & 15, l = lh >> 2, h = lh & 3;
    const float* wrow = lin_e_w + l * 16384 + k * 128 + h * 32;
    const float* arow = att_e + l * 128 + h * 32;
    float acc = 0.f;
#pragma unroll
    for (int c = 0; c < 32; c++) acc += wrow[c] * arow[c];
    w_e[k * 16 + lh] = acc;
}

// Mt[lh][r] : r<3 -> enc_edge_w row r composed with w_e col lh ; r==3 -> bias row
__global__ __launch_bounds__(64) void k_me(const float* __restrict__ encW,
                                           const float* __restrict__ encB,
                                           const float* __restrict__ w_e,
                                           float* __restrict__ Mt) {
    int idx = threadIdx.x;
    if (idx >= 64) return;
    int lh = idx >> 2, r = idx & 3;
    float acc = 0.f;
    for (int k = 0; k < 128; k++) {
        float a = (r < 3) ? encW[r * 128 + k] : encB[k];
        acc += a * w_e[k * 16 + lh];
    }
    Mt[lh * 4 + r] = acc;
}

// node encoder: h = x @ enc_node_w + b
__global__ __launch_bounds__(256) void k_enc(const float* __restrict__ x,
                                             const float* __restrict__ W,
                                             const float* __restrict__ b,
                                             float* __restrict__ h) {
    int i = blockIdx.x * 256 + threadIdx.x;
    if (i >= NN * 128) return;
    int n = i >> 7, c = i & 127;
    float acc = b[c];
    const float* xr = x + n * 8;
#pragma unroll
    for (int f = 0; f < 8; f++) acc += xr[f] * W[f * 128 + c];
    h[i] = acc;
}

__global__ __launch_bounds__(256) void k_deg(const int* __restrict__ dst, int* __restrict__ deg) {
    int e = blockIdx.x * 256 + threadIdx.x;
    if (e < EE) atomicAdd(&deg[dst[e]], 1);
}

// exclusive row_ptr over deg+1 (self-loop included); 4 elems/thread, 13 barrier iters
__global__ __launch_bounds__(1024) void k_scan(const int* __restrict__ deg, int* __restrict__ rp) {
    __shared__ int wsum[16];
    __shared__ int carry_sh;
    int tid = threadIdx.x, lane = tid & 63, wid = tid >> 6;
    if (tid == 0) { carry_sh = 0; rp[0] = 0; }
    __syncthreads();
    for (int base = 0; base < NN; base += 4096) {
        int i0 = base + tid * 4;
        int v0 = (i0 + 0 < NN) ? deg[i0 + 0] + 1 : 0;
        int v1 = (i0 + 1 < NN) ? deg[i0 + 1] + 1 : 0;
        int v2 = (i0 + 2 < NN) ? deg[i0 + 2] + 1 : 0;
        int v3 = (i0 + 3 < NN) ? deg[i0 + 3] + 1 : 0;
        int p1 = v0 + v1, p2 = p1 + v2, t = p2 + v3;
        int xv = t;
        for (int off = 1; off < 64; off <<= 1) {
            int s = __shfl_up(xv, off);
            if (lane >= off) xv += s;
        }
        if (lane == 63) wsum[wid] = xv;
        __syncthreads();
        if (wid == 0 && lane < 16) {
            int s = wsum[lane];
            for (int off = 1; off < 16; off <<= 1) {
                int u = __shfl_up(s, off);
                if (lane >= off) s += u;
            }
            wsum[lane] = s;
        }
        __syncthreads();
        int excl = carry_sh + (wid > 0 ? wsum[wid - 1] : 0) + xv - t;
        if (i0 + 0 < NN) rp[i0 + 1] = excl + v0;
        if (i0 + 1 < NN) rp[i0 + 2] = excl + p1;
        if (i0 + 2 < NN) rp[i0 + 3] = excl + p2;
        if (i0 + 3 < NN) rp[i0 + 4] = excl + t;
        __syncthreads();
        if (tid == 0) carry_sh += wsum[15];
        __syncthreads();
    }
}

// scatter edges into CSR slots; attr4 = (a0,a1,a2,1); accumulate per-dst attr sums
__global__ __launch_bounds__(256) void k_fill(const int* __restrict__ src, const int* __restrict__ dst,
                                              const float* __restrict__ edge_attr,
                                              const int* __restrict__ rp, int* __restrict__ fill,
                                              int* __restrict__ srcs, float* __restrict__ attr4,
                                              float* __restrict__ loopsum) {
    int e = blockIdx.x * 256 + threadIdx.x;
    if (e >= EE) return;
    int d = dst[e];
    int ofs = atomicAdd(&fill[d], 1);
    int pos = rp[d] + ofs;
    srcs[pos] = src[e];
    const float* ar = edge_attr + e * 3;
    float4 v = make_float4(ar[0], ar[1], ar[2], 1.f);
    *(float4*)(attr4 + pos * 4) = v;
    atomicAdd(&loopsum[d * 4 + 0], v.x);
    atomicAdd(&loopsum[d * 4 + 1], v.y);
    atomicAdd(&loopsum[d * 4 + 2], v.z);
}

// self-loop entry at the last CSR slot of each node: mean of incoming attr4
__global__ __launch_bounds__(256) void k_selfloop(const int* __restrict__ rp, int* __restrict__ srcs,
                                                  const float* __restrict__ loopsum,
                                                  float* __restrict__ attr4) {
    int n = blockIdx.x * 256 + threadIdx.x;
    if (n >= NN) return;
    int en = rp[n + 1];
    int d = en - rp[n] - 1;
    float inv = 1.f / fmaxf((float)d, 1.f);
    float4 v = make_float4(loopsum[n * 4] * inv, loopsum[n * 4 + 1] * inv,
                           loopsum[n * 4 + 2] * inv, d > 0 ? 1.f : 0.f);
    *(float4*)(attr4 + (en - 1) * 4) = v;
    srcs[en - 1] = n;
}

// xp = h @ lin_w  (50000x128 @ 128x128), xp stored bf16-packed; fused s/d epilogue
__global__ __launch_bounds__(256) void k_gemm(const float* __restrict__ hmat, const float* __restrict__ W,
                                              const float* __restrict__ a_src, const float* __restrict__ a_dst,
                                              uint* __restrict__ xpb, float* __restrict__ s_arr,
                                              float* __restrict__ d_arr) {
    __shared__ __align__(16) float Wl[64 * 128];   // 32 KB (k-chunked)
    __shared__ __align__(16) float A[32 * 132];    // 16.5 KB, +4 pad breaks bank aliasing
    int tid = threadIdx.x;
    int rowBase = blockIdx.x * 32;
    for (int idx = tid; idx < 1024; idx += 256) {
        int r = idx >> 5, c4 = (idx & 31) << 2;
        int gr = rowBase + r;
        float4 v = make_float4(0, 0, 0, 0);
        if (gr < NN) v = *(const float4*)(hmat + gr * 128 + c4);
        *(float4*)(&A[r * 132 + c4]) = v;
    }
    float4 acc[4];
    acc[0] = acc[1] = acc[2] = acc[3] = make_float4(0, 0, 0, 0);
    int rl = tid >> 5, c0 = (tid & 31) << 2;
    for (int kc = 0; kc < 2; kc++) {
        __syncthreads();
        for (int idx = tid; idx < 2048; idx += 256) {
            int r = idx >> 5, c4 = (idx & 31) << 2;
            *(float4*)(&Wl[r * 128 + c4]) = *(const float4*)(W + (kc * 64 + r) * 128 + c4);
        }
        __syncthreads();
        for (int kk = 0; kk < 64; kk += 4) {
            int kg = kc * 64 + kk;
            float4 a0 = *(float4*)(&A[rl * 132 + kg]);
            float4 a1 = *(float4*)(&A[(rl + 8) * 132 + kg]);
            float4 a2 = *(float4*)(&A[(rl + 16) * 132 + kg]);
            float4 a3 = *(float4*)(&A[(rl + 24) * 132 + kg]);
#pragma unroll
            for (int u = 0; u < 4; u++) {
                float4 w4 = *(float4*)(&Wl[(kk + u) * 128 + c0]);
                float b0 = (&a0.x)[u], b1 = (&a1.x)[u], b2 = (&a2.x)[u], b3 = (&a3.x)[u];
                acc[0].x += b0 * w4.x; acc[0].y += b0 * w4.y; acc[0].z += b0 * w4.z; acc[0].w += b0 * w4.w;
                acc[1].x += b1 * w4.x; acc[1].y += b1 * w4.y; acc[1].z += b1 * w4.z; acc[1].w += b1 * w4.w;
                acc[2].x += b2 * w4.x; acc[2].y += b2 * w4.y; acc[2].z += b2 * w4.z; acc[2].w += b2 * w4.w;
                acc[3].x += b3 * w4.x; acc[3].y += b3 * w4.y; acc[3].z += b3 * w4.z; acc[3].w += b3 * w4.w;
            }
        }
    }
    int hh = c0 >> 5, o = c0 & 31;
    float4 as = *(const float4*)(a_src + hh * 32 + o);
    float4 ad = *(const float4*)(a_dst + hh * 32 + o);
#pragma unroll
    for (int i = 0; i < 4; i++) {
        int gr = rowBase + rl + i * 8;
        if (gr < NN) {
            uint p0 = packbf(acc[i].x, acc[i].y);
            uint p1 = packbf(acc[i].z, acc[i].w);
            *(uint2*)(xpb + gr * 64 + (c0 >> 1)) = make_uint2(p0, p1);
        }
        float sp = acc[i].x * as.x + acc[i].y * as.y + acc[i].z * as.z + acc[i].w * as.w;
        float dp = acc[i].x * ad.x + acc[i].y * ad.y + acc[i].z * ad.z + acc[i].w * ad.w;
#pragma unroll
        for (int off = 1; off < 8; off <<= 1) { sp += __shfl_xor(sp, off); dp += __shfl_xor(dp, off); }
        if (((tid & 7) == 0) && gr < NN) { s_arr[gr * 4 + hh] = sp; d_arr[gr * 4 + hh] = dp; }
    }
}

// fused segment softmax (max-free: |alpha| small, exp(a)/sum exp(a) exact in fp32)
// + message aggregation with bf16 xp gather; one wave per destination node
__global__ __launch_bounds__(256) void k_edge(const int* __restrict__ rp, const int* __restrict__ srcs,
                                              const float* __restrict__ attr4, const float* __restrict__ Mt,
                                              const float* __restrict__ s_arr, const float* __restrict__ d_arr,
                                              const uint* __restrict__ xpb, float* __restrict__ out, int layer) {
    __shared__ __align__(16) float shw[4][4 * CAP];   // [wave][head*CAP + j]
    __shared__ __align__(16) int shs[4][CAP];
    int wid = threadIdx.x >> 6, lane = threadIdx.x & 63;
    int node = blockIdx.x * 4 + wid;
    if (node >= NN) return;
    int start = rp[node], end = rp[node + 1];
    int k = end - start;
    float4 d4 = *(const float4*)(d_arr + node * 4);
    float4 mt0 = *(const float4*)(Mt + (layer * 4 + 0) * 4);
    float4 mt1 = *(const float4*)(Mt + (layer * 4 + 1) * 4);
    float4 mt2 = *(const float4*)(Mt + (layer * 4 + 2) * 4);
    float4 mt3 = *(const float4*)(Mt + (layer * 4 + 3) * 4);
    float z0 = 0, z1 = 0, z2 = 0, z3 = 0;
    for (int base = 0; base < k; base += 64) {
        int j = base + lane;
        if (j < k) {
            int pos = start + j;
            int sv = srcs[pos];
            float4 s4 = *(const float4*)(s_arr + sv * 4);
            float4 a4 = *(const float4*)(attr4 + pos * 4);
            float e0 = a4.x * mt0.x + a4.y * mt0.y + a4.z * mt0.z + a4.w * mt0.w;
            float e1 = a4.x * mt1.x + a4.y * mt1.y + a4.z * mt1.z + a4.w * mt1.w;
            float e2 = a4.x * mt2.x + a4.y * mt2.y + a4.z * mt2.z + a4.w * mt2.w;
            float e3 = a4.x * mt3.x + a4.y * mt3.y + a4.z * mt3.z + a4.w * mt3.w;
            float al0 = s4.x + d4.x + e0; al0 = al0 > 0.f ? al0 : 0.2f * al0;
            float al1 = s4.y + d4.y + e1; al1 = al1 > 0.f ? al1 : 0.2f * al1;
            float al2 = s4.z + d4.z + e2; al2 = al2 > 0.f ? al2 : 0.2f * al2;
            float al3 = s4.w + d4.w + e3; al3 = al3 > 0.f ? al3 : 0.2f * al3;
            float w0 = __expf(al0), w1 = __expf(al1), w2 = __expf(al2), w3 = __expf(al3);
            z0 += w0; z1 += w1; z2 += w2; z3 += w3;
            if (j < CAP) {
                shs[wid][j] = sv;
                shw[wid][0 * CAP + j] = w0;
                shw[wid][1 * CAP + j] = w1;
                shw[wid][2 * CAP + j] = w2;
                shw[wid][3 * CAP + j] = w3;
            }
        }
    }
#pragma unroll
    for (int off = 32; off; off >>= 1) {
        z0 += __shfl_xor(z0, off); z1 += __shfl_xor(z1, off);
        z2 += __shfl_xor(z2, off); z3 += __shfl_xor(z3, off);
    }
    __builtin_amdgcn_wave_barrier();
    int hh = lane >> 4;                               // channels (2*lane, 2*lane+1) -> head
    float zi = 1.f / ((hh == 0 ? z0 : hh == 1 ? z1 : hh == 2 ? z2 : z3) + 1e-16f);
    float dh = hh == 0 ? d4.x : hh == 1 ? d4.y : hh == 2 ? d4.z : d4.w;
    float4 mth = hh == 0 ? mt0 : hh == 1 ? mt1 : hh == 2 ? mt2 : mt3;
    const float* wbase = &shw[wid][hh * CAP];
    const int* sbase = shs[wid];
    float acc0 = 0.f, acc1 = 0.f;
    int kc = k < CAP ? k : CAP;
    int j = 0;
    for (; j + 4 <= kc; j += 4) {
        int4 sv4 = *(const int4*)(sbase + j);
        float4 w4 = *(const float4*)(wbase + j);
        uint x0 = xpb[sv4.x * 64 + lane];
        uint x1 = xpb[sv4.y * 64 + lane];
        uint x2 = xpb[sv4.z * 64 + lane];
        uint x3 = xpb[sv4.w * 64 + lane];
        float2 f0 = bf2f(x0), f1 = bf2f(x1), f2 = bf2f(x2), f3 = bf2f(x3);
        acc0 += w4.x * f0.x + w4.y * f1.x + w4.z * f2.x + w4.w * f3.x;
        acc1 += w4.x * f0.y + w4.y * f1.y + w4.z * f2.y + w4.w * f3.y;
    }
    for (; j < kc; j++) {
        float w = wbase[j];
        int sv = sbase[j];
        float2 f = bf2f(xpb[sv * 64 + lane]);
        acc0 += w * f.x; acc1 += w * f.y;
    }
    for (; j < k; j++) {                              // deg > CAP fallback (recompute)
        int pos = start + j;
        int sv = srcs[pos];
        float s = s_arr[sv * 4 + hh];
        float4 a4 = *(const float4*)(attr4 + pos * 4);
        float ev = a4.x * mth.x + a4.y * mth.y + a4.z * mth.z + a4.w * mth.w;
        float a = s + dh + ev; a = a > 0.f ? a : 0.2f * a;
        float w = __expf(a);
        float2 f = bf2f(xpb[sv * 64 + lane]);
        acc0 += w * f.x; acc1 += w * f.y;
    }
    *(float2*)(out + node * 128 + lane * 2) = make_float2(acc0 * zi, acc1 * zi);
}

// BN stats: per-channel sum + sumsq  (gat_bias dropped: constant per channel, BN cancels it)
__global__ __launch_bounds__(256) void k_bnstats(const float* __restrict__ x, float* __restrict__ sums) {
    int tid = threadIdx.x;
    int c = tid & 127, half = tid >> 7;
    float s = 0.f, q = 0.f;
    for (int n = blockIdx.x * 2 + half; n < NN; n += gridDim.x * 2) {
        float v = x[n * 128 + c];
        s += v; q += v * v;
    }
    __shared__ float sh[256];
    sh[tid] = s; __syncthreads();
    if (tid < 128) atomicAdd(&sums[c], sh[tid] + sh[tid + 128]);
    __syncthreads();
    sh[tid] = q; __syncthreads();
    if (tid < 128) atomicAdd(&sums[128 + c], sh[tid] + sh[tid + 128]);
}

__global__ __launch_bounds__(256) void k_norm(const float* __restrict__ out, const float* __restrict__ sums,
                                              const float* __restrict__ gamma, const float* __restrict__ beta,
                                              float* __restrict__ h, int first) {
    int i = blockIdx.x * 256 + threadIdx.x;
    if (i >= NN * 128) return;
    int c = i & 127;
    float mu = sums[c] * (1.f / NN);
    float var = sums[128 + c] * (1.f / NN) - mu * mu;
    float iv = rsqrtf(fmaxf(var, 0.f) + 1e-5f);
    float v = (out[i] - mu) * iv * gamma[c] + beta[c];
    v = fmaxf(v, 0.f);
    h[i] = first ? v : h[i] + v;
}

__global__ __launch_bounds__(256) void k_cnt(const int* __restrict__ batch, int* __restrict__ cnt) {
    int n = blockIdx.x * 256 + threadIdx.x;
    if (n < NN) atomicAdd(&cnt[batch[n]], 1);
}

__global__ __launch_bounds__(256) void k_pool(const float* __restrict__ h, const int* __restrict__ batch,
                                              float* __restrict__ g) {
    int i = blockIdx.x * 256 + threadIdx.x;
    if (i >= NN * 128) return;
    int n = i >> 7, c = i & 127;
    atomicAdd(&g[batch[n] * 128 + c], h[i]);
}

__global__ __launch_bounds__(128) void k_fc(const float* __restrict__ g, const int* __restrict__ cnt,
                                            const float* __restrict__ w1, const float* __restrict__ b1,
                                            const float* __restrict__ w2, const float* __restrict__ b2,
                                            const float* __restrict__ w3, const float* __restrict__ b3,
                                            float* __restrict__ out) {
    __shared__ float gv[128];
    __shared__ float h1[128];
    __shared__ float h2[64];
    int gi = blockIdx.x, t = threadIdx.x;
    float c = fmaxf((float)cnt[gi], 1.f);
    gv[t] = g[gi * 128 + t] / c;
    __syncthreads();
    float acc = b1[t];
    for (int kk = 0; kk < 128; kk++) acc += gv[kk] * w1[kk * 128 + t];
    h1[t] = fmaxf(acc, 0.f);
    __syncthreads();
    if (t < 64) {
        float a2 = b2[t];
        for (int kk = 0; kk < 128; kk++) a2 += h1[kk] * w2[kk * 64 + t];
        h2[t] = fmaxf(a2, 0.f);
    }
    __syncthreads();
    if (t < 64) {
        float p = h2[t] * w3[t];
#pragma unroll
        for (int off = 32; off; off >>= 1) p += __shfl_xor(p, off);
        if (t == 0) out[gi] = p + b3[0];
    }
}

extern "C" void kernel_launch(void* const* d_in, const int* in_sizes, int n_in,
                              void* d_out, int out_size, void* d_ws, size_t ws_size,
                              hipStream_t stream) {
    const float* x            = (const float*)d_in[0];
    const float* edge_attr    = (const float*)d_in[1];
    const int*   edge_index   = (const int*)d_in[2];
    const int*   batch        = (const int*)d_in[3];
    const float* enc_node_w   = (const float*)d_in[4];
    const float* enc_node_b   = (const float*)d_in[5];
    const float* enc_edge_w   = (const float*)d_in[6];
    const float* enc_edge_b   = (const float*)d_in[7];
    const float* gat_lin_w    = (const float*)d_in[8];
    const float* gat_att_src  = (const float*)d_in[9];
    const float* gat_att_dst  = (const float*)d_in[10];
    const float* gat_lin_edge = (const float*)d_in[11];
    const float* gat_att_edge = (const float*)d_in[12];
    // d_in[13] = gat_bias: constant per channel before training-mode BN -> cancels, unused
    const float* bn_gamma     = (const float*)d_in[14];
    const float* bn_beta      = (const float*)d_in[15];
    const float* fc1_w        = (const float*)d_in[16];
    const float* fc1_b        = (const float*)d_in[17];
    const float* fc2_w        = (const float*)d_in[18];
    const float* fc2_b        = (const float*)d_in[19];
    const float* fc3_w        = (const float*)d_in[20];
    const float* fc3_b        = (const float*)d_in[21];
    float* outv = (float*)d_out;

    char* ws = (char*)d_ws;
    size_t off = 0;
    auto alloc = [&](size_t bytes) -> void* {
        void* p = ws + off;
        off = (off + bytes + 255) & ~(size_t)255;
        return p;
    };
    float* h       = (float*)alloc((size_t)NN * 128 * 4);
    float* gout    = (float*)alloc((size_t)NN * 128 * 4);
    uint*  xpb     = (uint*)alloc((size_t)NN * 64 * 4);     // bf16-packed xp
    float* s_arr   = (float*)alloc((size_t)NN * 4 * 4);
    float* d_arr   = (float*)alloc((size_t)NN * 4 * 4);
    int*   deg     = (int*)alloc((size_t)NN * 4);
    int*   fill    = (int*)alloc((size_t)NN * 4);
    int*   rp      = (int*)alloc((size_t)(NN + 1) * 4);
    int*   srcs    = (int*)alloc((size_t)ET * 4);
    float* attr4   = (float*)alloc((size_t)ET * 4 * 4);
    float* loopsum = (float*)alloc((size_t)NN * 4 * 4);
    float* w_e     = (float*)alloc(128 * 16 * 4);
    float* Mt      = (float*)alloc(64 * 4);
    float* bns     = (float*)alloc(256 * 4);
    float* g       = (float*)alloc((size_t)GG * 128 * 4);
    int*   cnt     = (int*)alloc((size_t)GG * 4);
    (void)ws_size; (void)in_sizes; (void)n_in; (void)out_size;

    hipMemsetAsync(deg, 0, NN * 4, stream);
    hipMemsetAsync(fill, 0, NN * 4, stream);
    hipMemsetAsync(loopsum, 0, (size_t)NN * 4 * 4, stream);
    hipMemsetAsync(g, 0, GG * 128 * 4, stream);
    hipMemsetAsync(cnt, 0, GG * 4, stream);

    const int* srce = edge_index;
    const int* dste = edge_index + EE;

    k_we<<<8, 256, 0, stream>>>(gat_lin_edge, gat_att_edge, w_e);
    k_me<<<1, 64, 0, stream>>>(enc_edge_w, enc_edge_b, w_e, Mt);
    k_enc<<<(NN * 128 + 255) / 256, 256, 0, stream>>>(x, enc_node_w, enc_node_b, h);
    k_deg<<<(EE + 255) / 256, 256, 0, stream>>>(dste, deg);
    k_scan<<<1, 1024, 0, stream>>>(deg, rp);
    k_fill<<<(EE + 255) / 256, 256, 0, stream>>>(srce, dste, edge_attr, rp, fill, srcs, attr4, loopsum);
    k_selfloop<<<(NN + 255) / 256, 256, 0, stream>>>(rp, srcs, loopsum, attr4);

    for (int l = 0; l < 4; l++) {
        k_gemm<<<(NN + 31) / 32, 256, 0, stream>>>(h, gat_lin_w + l * 16384,
                                                   gat_att_src + l * 128, gat_att_dst + l * 128,
                                                   xpb, s_arr, d_arr);
        k_edge<<<NN / 4, 256, 0, stream>>>(rp, srcs, attr4, Mt, s_arr, d_arr, xpb, gout, l);
        hipMemsetAsync(bns, 0, 256 * 4, stream);
        k_bnstats<<<256, 256, 0, stream>>>(gout, bns);
        k_norm<<<(NN * 128 + 255) / 256, 256, 0, stream>>>(gout, bns, bn_gamma + l * 128,
                                                           bn_beta + l * 128, h, l == 0 ? 1 : 0);
    }

    k_cnt<<<(NN + 255) / 256, 256, 0, stream>>>(batch, cnt);
    k_pool<<<(NN * 128 + 255) / 256, 256, 0, stream>>>(h, batch, g);
    k_fc<<<GG, 128, 0, stream>>>(g, cnt, fc1_w, fc1_b, fc2_w, fc2_b, fc3_w, fc3_b, outv);
}

// Round 3
// 758.936 us; speedup vs baseline: 1.1500x; 1.1093x over previous
//
#include <hip/hip_runtime.h>
#include <hip/hip_bf16.h>

#define NN 50000
#define EE 640000
#define ET (EE + NN)
#define GG 512
#define CAP 128

typedef unsigned int uint;

__device__ inline float2 bf2f(uint u) {
    return make_float2(__uint_as_float(u << 16), __uint_as_float(u & 0xffff0000u));
}
__device__ inline uint packbf(float a, float b) {
    __hip_bfloat162 t;
    t.x = __float2bfloat16(a);
    t.y = __float2bfloat16(b);
    return *(uint*)&t;
}

// ---------- precompute: w_e[k][l*4+h] = sum_c lin_e_w[l][k][h*32+c]*att_e[l][h][c]
__global__ __launch_bounds__(256) void k_we(const float* __restrict__ lin_e_w,
                                            const float* __restrict__ att_e,
                                            float* __restrict__ w_e) {
    int idx = blockIdx.x * 256 + threadIdx.x;
    if (idx >= 128 * 16) return;
    int k = idx >> 4, lh = idx & 15, l = lh >> 2, h = lh & 3;
    const float* wrow = lin_e_w + l * 16384 + k * 128 + h * 32;
    const float* arow = att_e + l * 128 + h * 32;
    float acc = 0.f;
#pragma unroll
    for (int c = 0; c < 32; c++) acc += wrow[c] * arow[c];
    w_e[k * 16 + lh] = acc;
}

// Mt[lh][r] : r<3 -> enc_edge_w row r composed with w_e col lh ; r==3 -> bias row
__global__ __launch_bounds__(64) void k_me(const float* __restrict__ encW,
                                           const float* __restrict__ encB,
                                           const float* __restrict__ w_e,
                                           float* __restrict__ Mt) {
    int idx = threadIdx.x;
    if (idx >= 64) return;
    int lh = idx >> 2, r = idx & 3;
    float acc = 0.f;
    for (int k = 0; k < 128; k++) {
        float a = (r < 3) ? encW[r * 128 + k] : encB[k];
        acc += a * w_e[k * 16 + lh];
    }
    Mt[lh * 4 + r] = acc;
}

// node encoder: h = x @ enc_node_w + b
__global__ __launch_bounds__(256) void k_enc(const float* __restrict__ x,
                                             const float* __restrict__ W,
                                             const float* __restrict__ b,
                                             float* __restrict__ h) {
    int i = blockIdx.x * 256 + threadIdx.x;
    if (i >= NN * 128) return;
    int n = i >> 7, c = i & 127;
    float acc = b[c];
    const float* xr = x + n * 8;
#pragma unroll
    for (int f = 0; f < 8; f++) acc += xr[f] * W[f * 128 + c];
    h[i] = acc;
}

__global__ __launch_bounds__(256) void k_deg(const int* __restrict__ dst, int* __restrict__ deg) {
    int e = blockIdx.x * 256 + threadIdx.x;
    if (e < EE) atomicAdd(&deg[dst[e]], 1);
}

// exclusive row_ptr over deg+1 (self-loop included); also fill[i] = rp[i] (slot cursor)
__global__ __launch_bounds__(1024) void k_scan(const int* __restrict__ deg, int* __restrict__ rp,
                                               int* __restrict__ fill) {
    __shared__ int wsum[16];
    __shared__ int carry_sh;
    int tid = threadIdx.x, lane = tid & 63, wid = tid >> 6;
    if (tid == 0) { carry_sh = 0; rp[0] = 0; }
    __syncthreads();
    for (int base = 0; base < NN; base += 4096) {
        int i0 = base + tid * 4;
        int v0 = (i0 + 0 < NN) ? deg[i0 + 0] + 1 : 0;
        int v1 = (i0 + 1 < NN) ? deg[i0 + 1] + 1 : 0;
        int v2 = (i0 + 2 < NN) ? deg[i0 + 2] + 1 : 0;
        int v3 = (i0 + 3 < NN) ? deg[i0 + 3] + 1 : 0;
        int p1 = v0 + v1, p2 = p1 + v2, t = p2 + v3;
        int xv = t;
        for (int off = 1; off < 64; off <<= 1) {
            int s = __shfl_up(xv, off);
            if (lane >= off) xv += s;
        }
        if (lane == 63) wsum[wid] = xv;
        __syncthreads();
        if (wid == 0 && lane < 16) {
            int s = wsum[lane];
            for (int off = 1; off < 16; off <<= 1) {
                int u = __shfl_up(s, off);
                if (lane >= off) s += u;
            }
            wsum[lane] = s;
        }
        __syncthreads();
        int excl = carry_sh + (wid > 0 ? wsum[wid - 1] : 0) + xv - t;
        if (i0 + 0 < NN) { rp[i0 + 1] = excl + v0; fill[i0 + 0] = excl; }
        if (i0 + 1 < NN) { rp[i0 + 2] = excl + p1; fill[i0 + 1] = excl + v0; }
        if (i0 + 2 < NN) { rp[i0 + 3] = excl + p2; fill[i0 + 2] = excl + p1; }
        if (i0 + 3 < NN) { rp[i0 + 4] = excl + t;  fill[i0 + 3] = excl + p2; }
        __syncthreads();
        if (tid == 0) carry_sh += wsum[15];
        __syncthreads();
    }
}

// scatter edges into CSR slots: ONE 16B record {src, a0, a1, a2} per edge
__global__ __launch_bounds__(256) void k_fill(const int* __restrict__ src, const int* __restrict__ dst,
                                              const float* __restrict__ edge_attr,
                                              int* __restrict__ fill, int* __restrict__ ed) {
    int e = blockIdx.x * 256 + threadIdx.x;
    if (e >= EE) return;
    int d = dst[e];
    int pos = atomicAdd(&fill[d], 1);
    const float* ar = edge_attr + e * 3;
    int4 rec = make_int4(src[e], __float_as_int(ar[0]), __float_as_int(ar[1]), __float_as_int(ar[2]));
    *(int4*)(ed + pos * 4) = rec;
}

// self-loop record at last CSR slot: mean of incoming attrs; 16 lanes/node coalesced
__global__ __launch_bounds__(256) void k_selfloop(const int* __restrict__ rp, int* __restrict__ ed) {
    int t = blockIdx.x * 256 + threadIdx.x;
    int n = t >> 4, sub = t & 15;
    if (n >= NN) return;
    int b = rp[n], en = rp[n + 1];
    int d = en - b - 1;
    float s0 = 0.f, s1 = 0.f, s2 = 0.f;
    for (int j = sub; j < d; j += 16) {
        int4 r = *(const int4*)(ed + (b + j) * 4);
        s0 += __int_as_float(r.y); s1 += __int_as_float(r.z); s2 += __int_as_float(r.w);
    }
#pragma unroll
    for (int off = 8; off; off >>= 1) {
        s0 += __shfl_xor(s0, off, 16);
        s1 += __shfl_xor(s1, off, 16);
        s2 += __shfl_xor(s2, off, 16);
    }
    if (sub == 0) {
        float inv = 1.f / fmaxf((float)d, 1.f);
        int4 rec = make_int4(n, __float_as_int(s0 * inv), __float_as_int(s1 * inv),
                             __float_as_int(s2 * inv));
        *(int4*)(ed + (en - 1) * 4) = rec;
    }
}

// xp = h @ lin_w  (50000x128 @ 128x128), xp stored bf16-packed; fused s/d epilogue
__global__ __launch_bounds__(256) void k_gemm(const float* __restrict__ hmat, const float* __restrict__ W,
                                              const float* __restrict__ a_src, const float* __restrict__ a_dst,
                                              uint* __restrict__ xpb, float* __restrict__ s_arr,
                                              float* __restrict__ d_arr) {
    __shared__ __align__(16) float Wl[64 * 128];   // 32 KB (k-chunked)
    __shared__ __align__(16) float A[32 * 132];    // 16.5 KB, +4 pad breaks bank aliasing
    int tid = threadIdx.x;
    int rowBase = blockIdx.x * 32;
    for (int idx = tid; idx < 1024; idx += 256) {
        int r = idx >> 5, c4 = (idx & 31) << 2;
        int gr = rowBase + r;
        float4 v = make_float4(0, 0, 0, 0);
        if (gr < NN) v = *(const float4*)(hmat + gr * 128 + c4);
        *(float4*)(&A[r * 132 + c4]) = v;
    }
    float4 acc[4];
    acc[0] = acc[1] = acc[2] = acc[3] = make_float4(0, 0, 0, 0);
    int rl = tid >> 5, c0 = (tid & 31) << 2;
    for (int kc = 0; kc < 2; kc++) {
        __syncthreads();
        for (int idx = tid; idx < 2048; idx += 256) {
            int r = idx >> 5, c4 = (idx & 31) << 2;
            *(float4*)(&Wl[r * 128 + c4]) = *(const float4*)(W + (kc * 64 + r) * 128 + c4);
        }
        __syncthreads();
        for (int kk = 0; kk < 64; kk += 4) {
            int kg = kc * 64 + kk;
            float4 a0 = *(float4*)(&A[rl * 132 + kg]);
            float4 a1 = *(float4*)(&A[(rl + 8) * 132 + kg]);
            float4 a2 = *(float4*)(&A[(rl + 16) * 132 + kg]);
            float4 a3 = *(float4*)(&A[(rl + 24) * 132 + kg]);
#pragma unroll
            for (int u = 0; u < 4; u++) {
                float4 w4 = *(float4*)(&Wl[(kk + u) * 128 + c0]);
                float b0 = (&a0.x)[u], b1 = (&a1.x)[u], b2 = (&a2.x)[u], b3 = (&a3.x)[u];
                acc[0].x += b0 * w4.x; acc[0].y += b0 * w4.y; acc[0].z += b0 * w4.z; acc[0].w += b0 * w4.w;
                acc[1].x += b1 * w4.x; acc[1].y += b1 * w4.y; acc[1].z += b1 * w4.z; acc[1].w += b1 * w4.w;
                acc[2].x += b2 * w4.x; acc[2].y += b2 * w4.y; acc[2].z += b2 * w4.z; acc[2].w += b2 * w4.w;
                acc[3].x += b3 * w4.x; acc[3].y += b3 * w4.y; acc[3].z += b3 * w4.z; acc[3].w += b3 * w4.w;
            }
        }
    }
    int hh = c0 >> 5, o = c0 & 31;
    float4 as = *(const float4*)(a_src + hh * 32 + o);
    float4 ad = *(const float4*)(a_dst + hh * 32 + o);
#pragma unroll
    for (int i = 0; i < 4; i++) {
        int gr = rowBase + rl + i * 8;
        if (gr < NN) {
            uint p0 = packbf(acc[i].x, acc[i].y);
            uint p1 = packbf(acc[i].z, acc[i].w);
            *(uint2*)(xpb + gr * 64 + (c0 >> 1)) = make_uint2(p0, p1);
        }
        float sp = acc[i].x * as.x + acc[i].y * as.y + acc[i].z * as.z + acc[i].w * as.w;
        float dp = acc[i].x * ad.x + acc[i].y * ad.y + acc[i].z * ad.z + acc[i].w * ad.w;
#pragma unroll
        for (int off = 1; off < 8; off <<= 1) { sp += __shfl_xor(sp, off); dp += __shfl_xor(dp, off); }
        if (((tid & 7) == 0) && gr < NN) { s_arr[gr * 4 + hh] = sp; d_arr[gr * 4 + hh] = dp; }
    }
}

// fused segment softmax (max-free: |alpha| small, exp(a)/sum exp(a) exact in fp32)
// + message aggregation with bf16 xp gather; one wave per destination node.
// CSR record per slot: {src, a0, a1, a2}; slot k-1 is the self-loop (w-flag = k>1).
__global__ __launch_bounds__(256) void k_edge(const int* __restrict__ rp, const int* __restrict__ ed,
                                              const float* __restrict__ Mt,
                                              const float* __restrict__ s_arr, const float* __restrict__ d_arr,
                                              const uint* __restrict__ xpb, float* __restrict__ out, int layer) {
    __shared__ __align__(16) float shw[4][4 * CAP];   // [wave][head*CAP + j]
    __shared__ __align__(16) int shs[4][CAP];
    int wid = threadIdx.x >> 6, lane = threadIdx.x & 63;
    int node = blockIdx.x * 4 + wid;
    if (node >= NN) return;
    int start = rp[node], end = rp[node + 1];
    int k = end - start;
    float loopw = (k > 1) ? 1.f : 0.f;                // self-loop w-flag (0 iff isolated node)
    float4 d4 = *(const float4*)(d_arr + node * 4);
    float4 mt0 = *(const float4*)(Mt + (layer * 4 + 0) * 4);
    float4 mt1 = *(const float4*)(Mt + (layer * 4 + 1) * 4);
    float4 mt2 = *(const float4*)(Mt + (layer * 4 + 2) * 4);
    float4 mt3 = *(const float4*)(Mt + (layer * 4 + 3) * 4);
    float z0 = 0, z1 = 0, z2 = 0, z3 = 0;
    for (int base = 0; base < k; base += 64) {
        int j = base + lane;
        if (j < k) {
            int4 r = *(const int4*)(ed + (start + j) * 4);
            int sv = r.x;
            float a0 = __int_as_float(r.y), a1 = __int_as_float(r.z), a2 = __int_as_float(r.w);
            float wf = (j < k - 1) ? 1.f : loopw;
            float4 s4 = *(const float4*)(s_arr + sv * 4);
            float e0 = a0 * mt0.x + a1 * mt0.y + a2 * mt0.z + wf * mt0.w;
            float e1 = a0 * mt1.x + a1 * mt1.y + a2 * mt1.z + wf * mt1.w;
            float e2 = a0 * mt2.x + a1 * mt2.y + a2 * mt2.z + wf * mt2.w;
            float e3 = a0 * mt3.x + a1 * mt3.y + a2 * mt3.z + wf * mt3.w;
            float al0 = s4.x + d4.x + e0; al0 = al0 > 0.f ? al0 : 0.2f * al0;
            float al1 = s4.y + d4.y + e1; al1 = al1 > 0.f ? al1 : 0.2f * al1;
            float al2 = s4.z + d4.z + e2; al2 = al2 > 0.f ? al2 : 0.2f * al2;
            float al3 = s4.w + d4.w + e3; al3 = al3 > 0.f ? al3 : 0.2f * al3;
            float w0 = __expf(al0), w1 = __expf(al1), w2 = __expf(al2), w3 = __expf(al3);
            z0 += w0; z1 += w1; z2 += w2; z3 += w3;
            if (j < CAP) {
                shs[wid][j] = sv;
                shw[wid][0 * CAP + j] = w0;
                shw[wid][1 * CAP + j] = w1;
                shw[wid][2 * CAP + j] = w2;
                shw[wid][3 * CAP + j] = w3;
            }
        }
    }
#pragma unroll
    for (int off = 32; off; off >>= 1) {
        z0 += __shfl_xor(z0, off); z1 += __shfl_xor(z1, off);
        z2 += __shfl_xor(z2, off); z3 += __shfl_xor(z3, off);
    }
    __builtin_amdgcn_wave_barrier();
    int hh = lane >> 4;                               // channels (2*lane, 2*lane+1) -> head
    float zi = 1.f / ((hh == 0 ? z0 : hh == 1 ? z1 : hh == 2 ? z2 : z3) + 1e-16f);
    float dh = hh == 0 ? d4.x : hh == 1 ? d4.y : hh == 2 ? d4.z : d4.w;
    float4 mth = hh == 0 ? mt0 : hh == 1 ? mt1 : hh == 2 ? mt2 : mt3;
    const float* wbase = &shw[wid][hh * CAP];
    const int* sbase = shs[wid];
    float acc0 = 0.f, acc1 = 0.f;
    int kc = k < CAP ? k : CAP;
    int j = 0;
    for (; j + 4 <= kc; j += 4) {
        int4 sv4 = *(const int4*)(sbase + j);
        float4 w4 = *(const float4*)(wbase + j);
        uint x0 = xpb[sv4.x * 64 + lane];
        uint x1 = xpb[sv4.y * 64 + lane];
        uint x2 = xpb[sv4.z * 64 + lane];
        uint x3 = xpb[sv4.w * 64 + lane];
        float2 f0 = bf2f(x0), f1 = bf2f(x1), f2 = bf2f(x2), f3 = bf2f(x3);
        acc0 += w4.x * f0.x + w4.y * f1.x + w4.z * f2.x + w4.w * f3.x;
        acc1 += w4.x * f0.y + w4.y * f1.y + w4.z * f2.y + w4.w * f3.y;
    }
    for (; j < kc; j++) {
        float w = wbase[j];
        int sv = sbase[j];
        float2 f = bf2f(xpb[sv * 64 + lane]);
        acc0 += w * f.x; acc1 += w * f.y;
    }
    for (; j < k; j++) {                              // deg > CAP fallback (recompute)
        int4 r = *(const int4*)(ed + (start + j) * 4);
        int sv = r.x;
        float a0 = __int_as_float(r.y), a1 = __int_as_float(r.z), a2 = __int_as_float(r.w);
        float wf = (j < k - 1) ? 1.f : loopw;
        float s = s_arr[sv * 4 + hh];
        float ev = a0 * mth.x + a1 * mth.y + a2 * mth.z + wf * mth.w;
        float a = s + dh + ev; a = a > 0.f ? a : 0.2f * a;
        float w = __expf(a);
        float2 f = bf2f(xpb[sv * 64 + lane]);
        acc0 += w * f.x; acc1 += w * f.y;
    }
    *(float2*)(out + node * 128 + lane * 2) = make_float2(acc0 * zi, acc1 * zi);
}

// BN stats: per-channel sum + sumsq  (gat_bias dropped: constant per channel, BN cancels it)
__global__ __launch_bounds__(256) void k_bnstats(const float* __restrict__ x, float* __restrict__ sums) {
    int tid = threadIdx.x;
    int c = tid & 127, half = tid >> 7;
    float s = 0.f, q = 0.f;
    for (int n = blockIdx.x * 2 + half; n < NN; n += gridDim.x * 2) {
        float v = x[n * 128 + c];
        s += v; q += v * v;
    }
    __shared__ float sh[256];
    sh[tid] = s; __syncthreads();
    if (tid < 128) atomicAdd(&sums[c], sh[tid] + sh[tid + 128]);
    __syncthreads();
    sh[tid] = q; __syncthreads();
    if (tid < 128) atomicAdd(&sums[128 + c], sh[tid] + sh[tid + 128]);
}

__global__ __launch_bounds__(256) void k_norm(const float* __restrict__ out, const float* __restrict__ sums,
                                              const float* __restrict__ gamma, const float* __restrict__ beta,
                                              float* __restrict__ h, int first) {
    int i = blockIdx.x * 256 + threadIdx.x;
    if (i >= NN * 128) return;
    int c = i & 127;
    float mu = sums[c] * (1.f / NN);
    float var = sums[128 + c] * (1.f / NN) - mu * mu;
    float iv = rsqrtf(fmaxf(var, 0.f) + 1e-5f);
    float v = (out[i] - mu) * iv * gamma[c] + beta[c];
    v = fmaxf(v, 0.f);
    h[i] = first ? v : h[i] + v;
}

__global__ __launch_bounds__(256) void k_cnt(const int* __restrict__ batch, int* __restrict__ cnt) {
    int n = blockIdx.x * 256 + threadIdx.x;
    if (n < NN) atomicAdd(&cnt[batch[n]], 1);
}

__global__ __launch_bounds__(256) void k_pool(const float* __restrict__ h, const int* __restrict__ batch,
                                              float* __restrict__ g) {
    int i = blockIdx.x * 256 + threadIdx.x;
    if (i >= NN * 128) return;
    int n = i >> 7, c = i & 127;
    atomicAdd(&g[batch[n] * 128 + c], h[i]);
}

__global__ __launch_bounds__(128) void k_fc(const float* __restrict__ g, const int* __restrict__ cnt,
                                            const float* __restrict__ w1, const float* __restrict__ b1,
                                            const float* __restrict__ w2, const float* __restrict__ b2,
                                            const float* __restrict__ w3, const float* __restrict__ b3,
                                            float* __restrict__ out) {
    __shared__ float gv[128];
    __shared__ float h1[128];
    __shared__ float h2[64];
    int gi = blockIdx.x, t = threadIdx.x;
    float c = fmaxf((float)cnt[gi], 1.f);
    gv[t] = g[gi * 128 + t] / c;
    __syncthreads();
    float acc = b1[t];
    for (int kk = 0; kk < 128; kk++) acc += gv[kk] * w1[kk * 128 + t];
    h1[t] = fmaxf(acc, 0.f);
    __syncthreads();
    if (t < 64) {
        float a2 = b2[t];
        for (int kk = 0; kk < 128; kk++) a2 += h1[kk] * w2[kk * 64 + t];
        h2[t] = fmaxf(a2, 0.f);
    }
    __syncthreads();
    if (t < 64) {
        float p = h2[t] * w3[t];
#pragma unroll
        for (int off = 32; off; off >>= 1) p += __shfl_xor(p, off);
        if (t == 0) out[gi] = p + b3[0];
    }
}

extern "C" void kernel_launch(void* const* d_in, const int* in_sizes, int n_in,
                              void* d_out, int out_size, void* d_ws, size_t ws_size,
                              hipStream_t stream) {
    const float* x            = (const float*)d_in[0];
    const float* edge_attr    = (const float*)d_in[1];
    const int*   edge_index   = (const int*)d_in[2];
    const int*   batch        = (const int*)d_in[3];
    const float* enc_node_w   = (const float*)d_in[4];
    const float* enc_node_b   = (const float*)d_in[5];
    const float* enc_edge_w   = (const float*)d_in[6];
    const float* enc_edge_b   = (const float*)d_in[7];
    const float* gat_lin_w    = (const float*)d_in[8];
    const float* gat_att_src  = (const float*)d_in[9];
    const float* gat_att_dst  = (const float*)d_in[10];
    const float* gat_lin_edge = (const float*)d_in[11];
    const float* gat_att_edge = (const float*)d_in[12];
    // d_in[13] = gat_bias: constant per channel before training-mode BN -> cancels, unused
    const float* bn_gamma     = (const float*)d_in[14];
    const float* bn_beta      = (const float*)d_in[15];
    const float* fc1_w        = (const float*)d_in[16];
    const float* fc1_b        = (const float*)d_in[17];
    const float* fc2_w        = (const float*)d_in[18];
    const float* fc2_b        = (const float*)d_in[19];
    const float* fc3_w        = (const float*)d_in[20];
    const float* fc3_b        = (const float*)d_in[21];
    float* outv = (float*)d_out;

    char* ws = (char*)d_ws;
    size_t off = 0;
    auto alloc = [&](size_t bytes) -> void* {
        void* p = ws + off;
        off = (off + bytes + 255) & ~(size_t)255;
        return p;
    };
    float* h       = (float*)alloc((size_t)NN * 128 * 4);
    float* gout    = (float*)alloc((size_t)NN * 128 * 4);
    uint*  xpb     = (uint*)alloc((size_t)NN * 64 * 4);     // bf16-packed xp
    float* s_arr   = (float*)alloc((size_t)NN * 4 * 4);
    float* d_arr   = (float*)alloc((size_t)NN * 4 * 4);
    int*   deg     = (int*)alloc((size_t)NN * 4);
    int*   fill    = (int*)alloc((size_t)NN * 4);
    int*   rp      = (int*)alloc((size_t)(NN + 1) * 4);
    int*   ed      = (int*)alloc((size_t)ET * 4 * 4);       // CSR records {src,a0,a1,a2}
    float* w_e     = (float*)alloc(128 * 16 * 4);
    float* Mt      = (float*)alloc(64 * 4);
    float* bns     = (float*)alloc(256 * 4);
    float* g       = (float*)alloc((size_t)GG * 128 * 4);
    int*   cnt     = (int*)alloc((size_t)GG * 4);
    (void)ws_size; (void)in_sizes; (void)n_in; (void)out_size;

    hipMemsetAsync(deg, 0, NN * 4, stream);
    hipMemsetAsync(g, 0, GG * 128 * 4, stream);
    hipMemsetAsync(cnt, 0, GG * 4, stream);

    const int* srce = edge_index;
    const int* dste = edge_index + EE;

    k_we<<<8, 256, 0, stream>>>(gat_lin_edge, gat_att_edge, w_e);
    k_me<<<1, 64, 0, stream>>>(enc_edge_w, enc_edge_b, w_e, Mt);
    k_enc<<<(NN * 128 + 255) / 256, 256, 0, stream>>>(x, enc_node_w, enc_node_b, h);
    k_deg<<<(EE + 255) / 256, 256, 0, stream>>>(dste, deg);
    k_scan<<<1, 1024, 0, stream>>>(deg, rp, fill);
    k_fill<<<(EE + 255) / 256, 256, 0, stream>>>(srce, dste, edge_attr, fill, ed);
    k_selfloop<<<(NN * 16 + 255) / 256, 256, 0, stream>>>(rp, ed);

    for (int l = 0; l < 4; l++) {
        k_gemm<<<(NN + 31) / 32, 256, 0, stream>>>(h, gat_lin_w + l * 16384,
                                                   gat_att_src + l * 128, gat_att_dst + l * 128,
                                                   xpb, s_arr, d_arr);
        k_edge<<<NN / 4, 256, 0, stream>>>(rp, ed, Mt, s_arr, d_arr, xpb, gout, l);
        hipMemsetAsync(bns, 0, 256 * 4, stream);
        k_bnstats<<<256, 256, 0, stream>>>(gout, bns);
        k_norm<<<(NN * 128 + 255) / 256, 256, 0, stream>>>(gout, bns, bn_gamma + l * 128,
                                                           bn_beta + l * 128, h, l == 0 ? 1 : 0);
    }

    k_cnt<<<(NN + 255) / 256, 256, 0, stream>>>(batch, cnt);
    k_pool<<<(NN * 128 + 255) / 256, 256, 0, stream>>>(h, batch, g);
    k_fc<<<GG, 128, 0, stream>>>(g, cnt, fc1_w, fc1_b, fc2_w, fc2_b, fc3_w, fc3_b, outv);
}

// Round 4
// 659.219 us; speedup vs baseline: 1.3239x; 1.1513x over previous
//
#include <hip/hip_runtime.h>
#include <hip/hip_bf16.h>

#define NN 50000
#define EE 640000
#define ET (EE + NN)
#define GG 512
#define CAP 128

typedef unsigned int uint;
typedef __attribute__((ext_vector_type(8))) short short8;
typedef __attribute__((ext_vector_type(4))) float floatx4;

__device__ inline float2 bf2f(uint u) {
    return make_float2(__uint_as_float(u << 16), __uint_as_float(u & 0xffff0000u));
}
__device__ inline uint packbf(float a, float b) {
    __hip_bfloat162 t;
    t.x = __float2bfloat16(a);
    t.y = __float2bfloat16(b);
    return *(uint*)&t;
}

// ---------- precompute: w_e[k][l*4+h] = sum_c lin_e_w[l][k][h*32+c]*att_e[l][h][c]
__global__ __launch_bounds__(256) void k_we(const float* __restrict__ lin_e_w,
                                            const float* __restrict__ att_e,
                                            float* __restrict__ w_e) {
    int idx = blockIdx.x * 256 + threadIdx.x;
    if (idx >= 128 * 16) return;
    int k = idx >> 4, lh = idx & 15, l = lh >> 2, h = lh & 3;
    const float* wrow = lin_e_w + l * 16384 + k * 128 + h * 32;
    const float* arow = att_e + l * 128 + h * 32;
    float acc = 0.f;
#pragma unroll
    for (int c = 0; c < 32; c++) acc += wrow[c] * arow[c];
    w_e[k * 16 + lh] = acc;
}

// Mt[lh][r] : r<3 -> enc_edge_w row r composed with w_e col lh ; r==3 -> bias row
__global__ __launch_bounds__(64) void k_me(const float* __restrict__ encW,
                                           const float* __restrict__ encB,
                                           const float* __restrict__ w_e,
                                           float* __restrict__ Mt) {
    int idx = threadIdx.x;
    if (idx >= 64) return;
    int lh = idx >> 2, r = idx & 3;
    float acc = 0.f;
    for (int k = 0; k < 128; k++) {
        float a = (r < 3) ? encW[r * 128 + k] : encB[k];
        acc += a * w_e[k * 16 + lh];
    }
    Mt[lh * 4 + r] = acc;
}

// transpose+convert gat_lin_w to bf16: WbT[l][n][k] (k-major pairs packed in uint)
__global__ __launch_bounds__(256) void k_wcvt(const float* __restrict__ W, uint* __restrict__ WbT) {
    int idx = blockIdx.x * 256 + threadIdx.x;
    if (idx >= 4 * 128 * 64) return;
    int l = idx >> 13, rem = idx & 8191, n = rem >> 6, u = rem & 63;
    const float* Wl = W + l * 16384;
    float k0 = Wl[(2 * u) * 128 + n];
    float k1 = Wl[(2 * u + 1) * 128 + n];
    WbT[idx] = packbf(k0, k1);
}

// node encoder: h = x @ enc_node_w + b (fp32 + bf16-packed copies)
__global__ __launch_bounds__(256) void k_enc(const float* __restrict__ x,
                                             const float* __restrict__ W,
                                             const float* __restrict__ b,
                                             float* __restrict__ h, uint* __restrict__ hb) {
    int idx = blockIdx.x * 256 + threadIdx.x;
    if (idx >= NN * 64) return;
    int n = idx >> 6, c0 = (idx & 63) * 2;
    float a0 = b[c0], a1 = b[c0 + 1];
    const float* xr = x + n * 8;
#pragma unroll
    for (int f = 0; f < 8; f++) {
        a0 += xr[f] * W[f * 128 + c0];
        a1 += xr[f] * W[f * 128 + c0 + 1];
    }
    *(float2*)(h + n * 128 + c0) = make_float2(a0, a1);
    hb[idx] = packbf(a0, a1);
}

// degree count, 4 edges/thread for MLP
__global__ __launch_bounds__(256) void k_deg(const int* __restrict__ dst, int* __restrict__ deg) {
    int e0 = (blockIdx.x * 256 + threadIdx.x) * 4;
    if (e0 >= EE) return;
    int4 d4 = *(const int4*)(dst + e0);
    atomicAdd(&deg[d4.x], 1);
    atomicAdd(&deg[d4.y], 1);
    atomicAdd(&deg[d4.z], 1);
    atomicAdd(&deg[d4.w], 1);
}

// exclusive row_ptr over deg+1 (self-loop included); also fill[i] = rp[i] (slot cursor)
__global__ __launch_bounds__(1024) void k_scan(const int* __restrict__ deg, int* __restrict__ rp,
                                               int* __restrict__ fill) {
    __shared__ int wsum[16];
    __shared__ int carry_sh;
    int tid = threadIdx.x, lane = tid & 63, wid = tid >> 6;
    if (tid == 0) { carry_sh = 0; rp[0] = 0; }
    __syncthreads();
    for (int base = 0; base < NN; base += 4096) {
        int i0 = base + tid * 4;
        int v0 = (i0 + 0 < NN) ? deg[i0 + 0] + 1 : 0;
        int v1 = (i0 + 1 < NN) ? deg[i0 + 1] + 1 : 0;
        int v2 = (i0 + 2 < NN) ? deg[i0 + 2] + 1 : 0;
        int v3 = (i0 + 3 < NN) ? deg[i0 + 3] + 1 : 0;
        int p1 = v0 + v1, p2 = p1 + v2, t = p2 + v3;
        int xv = t;
        for (int off = 1; off < 64; off <<= 1) {
            int s = __shfl_up(xv, off);
            if (lane >= off) xv += s;
        }
        if (lane == 63) wsum[wid] = xv;
        __syncthreads();
        if (wid == 0 && lane < 16) {
            int s = wsum[lane];
            for (int off = 1; off < 16; off <<= 1) {
                int u = __shfl_up(s, off);
                if (lane >= off) s += u;
            }
            wsum[lane] = s;
        }
        __syncthreads();
        int excl = carry_sh + (wid > 0 ? wsum[wid - 1] : 0) + xv - t;
        if (i0 + 0 < NN) { rp[i0 + 1] = excl + v0; fill[i0 + 0] = excl; }
        if (i0 + 1 < NN) { rp[i0 + 2] = excl + p1; fill[i0 + 1] = excl + v0; }
        if (i0 + 2 < NN) { rp[i0 + 3] = excl + p2; fill[i0 + 2] = excl + p1; }
        if (i0 + 3 < NN) { rp[i0 + 4] = excl + t;  fill[i0 + 3] = excl + p2; }
        __syncthreads();
        if (tid == 0) carry_sh += wsum[15];
        __syncthreads();
    }
}

// scatter edges into CSR slots, 4 edges/thread: ONE 16B record {src, a0, a1, a2} per edge
__global__ __launch_bounds__(256) void k_fill(const int* __restrict__ src, const int* __restrict__ dst,
                                              const float* __restrict__ edge_attr,
                                              int* __restrict__ fill, int* __restrict__ ed) {
    int e0 = (blockIdx.x * 256 + threadIdx.x) * 4;
    if (e0 >= EE) return;
    int4 d4 = *(const int4*)(dst + e0);
    int4 s4 = *(const int4*)(src + e0);
    const float* ar = edge_attr + (size_t)e0 * 3;
    float4 f0 = *(const float4*)(ar + 0);
    float4 f1 = *(const float4*)(ar + 4);
    float4 f2 = *(const float4*)(ar + 8);
    int p0 = atomicAdd(&fill[d4.x], 1);
    int p1 = atomicAdd(&fill[d4.y], 1);
    int p2 = atomicAdd(&fill[d4.z], 1);
    int p3 = atomicAdd(&fill[d4.w], 1);
    *(int4*)(ed + (size_t)p0 * 4) = make_int4(s4.x, __float_as_int(f0.x), __float_as_int(f0.y), __float_as_int(f0.z));
    *(int4*)(ed + (size_t)p1 * 4) = make_int4(s4.y, __float_as_int(f0.w), __float_as_int(f1.x), __float_as_int(f1.y));
    *(int4*)(ed + (size_t)p2 * 4) = make_int4(s4.z, __float_as_int(f1.z), __float_as_int(f1.w), __float_as_int(f2.x));
    *(int4*)(ed + (size_t)p3 * 4) = make_int4(s4.w, __float_as_int(f2.y), __float_as_int(f2.z), __float_as_int(f2.w));
}

// self-loop record at last CSR slot: mean of incoming attrs; 16 lanes/node coalesced
__global__ __launch_bounds__(256) void k_selfloop(const int* __restrict__ rp, int* __restrict__ ed) {
    int t = blockIdx.x * 256 + threadIdx.x;
    int n = t >> 4, sub = t & 15;
    if (n >= NN) return;
    int b = rp[n], en = rp[n + 1];
    int d = en - b - 1;
    float s0 = 0.f, s1 = 0.f, s2 = 0.f;
    for (int j = sub; j < d; j += 16) {
        int4 r = *(const int4*)(ed + (size_t)(b + j) * 4);
        s0 += __int_as_float(r.y); s1 += __int_as_float(r.z); s2 += __int_as_float(r.w);
    }
#pragma unroll
    for (int off = 8; off; off >>= 1) {
        s0 += __shfl_xor(s0, off, 16);
        s1 += __shfl_xor(s1, off, 16);
        s2 += __shfl_xor(s2, off, 16);
    }
    if (sub == 0) {
        float inv = 1.f / fmaxf((float)d, 1.f);
        *(int4*)(ed + (size_t)(en - 1) * 4) =
            make_int4(n, __float_as_int(s0 * inv), __float_as_int(s1 * inv), __float_as_int(s2 * inv));
    }
}

// MFMA GEMM: xp = h @ lin_w (bf16 in, fp32 acc, bf16-packed out) + fused s/d epilogue.
// Block = 4 waves x 16 rows = 64 rows; full 128-col output per wave; K=128 in 4 chunks of 32.
__global__ __launch_bounds__(256) void k_gemm(const uint* __restrict__ hb, const uint* __restrict__ WbT,
                                              const float* __restrict__ a_src, const float* __restrict__ a_dst,
                                              uint* __restrict__ xpb, float* __restrict__ s_arr,
                                              float* __restrict__ d_arr) {
    __shared__ __align__(16) uint Bl[128 * 68];   // [n][k], row stride 68 uints (64 + 4 pad)
    int tid = threadIdx.x;
    for (int idx = tid; idx < 2048; idx += 256) {   // stage 32KB WbT
        int n = idx >> 4, u4 = idx & 15;
        uint4 v = *(const uint4*)(WbT + n * 64 + u4 * 4);
        *(uint4*)(&Bl[n * 68 + u4 * 4]) = v;
    }
    int lane = tid & 63, wv = tid >> 6;
    int ln15 = lane & 15, quad = lane >> 4;
    int rowBase = blockIdx.x * 64 + wv * 16;
    int rowA = rowBase + ln15;                      // A-frag row this lane loads
    int rowAc = rowA < NN ? rowA : 0;
    __syncthreads();
    short8 af[4];
#pragma unroll
    for (int c = 0; c < 4; c++)
        af[c] = *(const short8*)((const short*)hb + (size_t)rowAc * 128 + c * 32 + quad * 8);
    floatx4 acc[8];
#pragma unroll
    for (int t = 0; t < 8; t++) acc[t] = (floatx4){0.f, 0.f, 0.f, 0.f};
#pragma unroll
    for (int c = 0; c < 4; c++) {
#pragma unroll
        for (int t = 0; t < 8; t++) {
            short8 bf = *(const short8*)((const short*)&Bl[(16 * t + ln15) * 68] + c * 32 + quad * 8);
            acc[t] = __builtin_amdgcn_mfma_f32_16x16x32_bf16(af[c], bf, acc[t], 0, 0, 0);
        }
    }
    // C/D layout: col = 16t + (lane&15), row = rowBase + quad*4 + reg
#pragma unroll
    for (int t = 0; t < 8; t++) {
#pragma unroll
        for (int r = 0; r < 4; r++) {
            float v = acc[t][r];
            float vhi = __shfl_xor(v, 1);           // neighbor col (lane^1)
            int grow = rowBase + quad * 4 + r;
            if (!(ln15 & 1) && grow < NN)
                xpb[(size_t)grow * 64 + 8 * t + (ln15 >> 1)] = packbf(v, vhi);
        }
    }
    // s/d attention dots: head hh covers tiles 2hh (cols 32hh+ln15) and 2hh+1 (cols 32hh+16+ln15)
    float asl[4], ash[4], adl[4], adh[4];
#pragma unroll
    for (int hh = 0; hh < 4; hh++) {
        asl[hh] = a_src[hh * 32 + ln15]; ash[hh] = a_src[hh * 32 + 16 + ln15];
        adl[hh] = a_dst[hh * 32 + ln15]; adh[hh] = a_dst[hh * 32 + 16 + ln15];
    }
#pragma unroll
    for (int r = 0; r < 4; r++) {
        float s0 = acc[0][r] * asl[0] + acc[1][r] * ash[0];
        float s1 = acc[2][r] * asl[1] + acc[3][r] * ash[1];
        float s2 = acc[4][r] * asl[2] + acc[5][r] * ash[2];
        float s3 = acc[6][r] * asl[3] + acc[7][r] * ash[3];
        float d0 = acc[0][r] * adl[0] + acc[1][r] * adh[0];
        float d1 = acc[2][r] * adl[1] + acc[3][r] * adh[1];
        float d2 = acc[4][r] * adl[2] + acc[5][r] * adh[2];
        float d3 = acc[6][r] * adl[3] + acc[7][r] * adh[3];
#pragma unroll
        for (int off = 1; off < 16; off <<= 1) {
            s0 += __shfl_xor(s0, off); s1 += __shfl_xor(s1, off);
            s2 += __shfl_xor(s2, off); s3 += __shfl_xor(s3, off);
            d0 += __shfl_xor(d0, off); d1 += __shfl_xor(d1, off);
            d2 += __shfl_xor(d2, off); d3 += __shfl_xor(d3, off);
        }
        int grow = rowBase + quad * 4 + r;
        if (ln15 == 0 && grow < NN) {
            *(float4*)(s_arr + grow * 4) = make_float4(s0, s1, s2, s3);
            *(float4*)(d_arr + grow * 4) = make_float4(d0, d1, d2, d3);
        }
    }
}

// fused segment softmax (max-free: |alpha| small, exp(a)/sum exp(a) exact in fp32)
// + message aggregation with bf16 xp gather; one wave per destination node.
// CSR record per slot: {src, a0, a1, a2}; slot k-1 is the self-loop (w-flag = k>1).
__global__ __launch_bounds__(256) void k_edge(const int* __restrict__ rp, const int* __restrict__ ed,
                                              const float* __restrict__ Mt,
                                              const float* __restrict__ s_arr, const float* __restrict__ d_arr,
                                              const uint* __restrict__ xpb, float* __restrict__ out, int layer) {
    __shared__ __align__(16) float shw[4][4 * CAP];   // [wave][head*CAP + j]
    __shared__ __align__(16) int shs[4][CAP];
    int wid = threadIdx.x >> 6, lane = threadIdx.x & 63;
    int node = blockIdx.x * 4 + wid;
    if (node >= NN) return;
    int start = rp[node], end = rp[node + 1];
    int k = end - start;
    float loopw = (k > 1) ? 1.f : 0.f;                // self-loop w-flag (0 iff isolated node)
    float4 d4 = *(const float4*)(d_arr + node * 4);
    float4 mt0 = *(const float4*)(Mt + (layer * 4 + 0) * 4);
    float4 mt1 = *(const float4*)(Mt + (layer * 4 + 1) * 4);
    float4 mt2 = *(const float4*)(Mt + (layer * 4 + 2) * 4);
    float4 mt3 = *(const float4*)(Mt + (layer * 4 + 3) * 4);
    float z0 = 0, z1 = 0, z2 = 0, z3 = 0;
    for (int base = 0; base < k; base += 64) {
        int j = base + lane;
        if (j < k) {
            int4 r = *(const int4*)(ed + (size_t)(start + j) * 4);
            int sv = r.x;
            float a0 = __int_as_float(r.y), a1 = __int_as_float(r.z), a2 = __int_as_float(r.w);
            float wf = (j < k - 1) ? 1.f : loopw;
            float4 s4 = *(const float4*)(s_arr + sv * 4);
            float e0 = a0 * mt0.x + a1 * mt0.y + a2 * mt0.z + wf * mt0.w;
            float e1 = a0 * mt1.x + a1 * mt1.y + a2 * mt1.z + wf * mt1.w;
            float e2 = a0 * mt2.x + a1 * mt2.y + a2 * mt2.z + wf * mt2.w;
            float e3 = a0 * mt3.x + a1 * mt3.y + a2 * mt3.z + wf * mt3.w;
            float al0 = s4.x + d4.x + e0; al0 = al0 > 0.f ? al0 : 0.2f * al0;
            float al1 = s4.y + d4.y + e1; al1 = al1 > 0.f ? al1 : 0.2f * al1;
            float al2 = s4.z + d4.z + e2; al2 = al2 > 0.f ? al2 : 0.2f * al2;
            float al3 = s4.w + d4.w + e3; al3 = al3 > 0.f ? al3 : 0.2f * al3;
            float w0 = __expf(al0), w1 = __expf(al1), w2 = __expf(al2), w3 = __expf(al3);
            z0 += w0; z1 += w1; z2 += w2; z3 += w3;
            if (j < CAP) {
                shs[wid][j] = sv;
                shw[wid][0 * CAP + j] = w0;
                shw[wid][1 * CAP + j] = w1;
                shw[wid][2 * CAP + j] = w2;
                shw[wid][3 * CAP + j] = w3;
            }
        }
    }
#pragma unroll
    for (int off = 32; off; off >>= 1) {
        z0 += __shfl_xor(z0, off); z1 += __shfl_xor(z1, off);
        z2 += __shfl_xor(z2, off); z3 += __shfl_xor(z3, off);
    }
    __builtin_amdgcn_wave_barrier();
    int hh = lane >> 4;                               // channels (2*lane, 2*lane+1) -> head
    float zi = 1.f / ((hh == 0 ? z0 : hh == 1 ? z1 : hh == 2 ? z2 : z3) + 1e-16f);
    float dh = hh == 0 ? d4.x : hh == 1 ? d4.y : hh == 2 ? d4.z : d4.w;
    float4 mth = hh == 0 ? mt0 : hh == 1 ? mt1 : hh == 2 ? mt2 : mt3;
    const float* wbase = &shw[wid][hh * CAP];
    const int* sbase = shs[wid];
    float acc0 = 0.f, acc1 = 0.f;
    int kc = k < CAP ? k : CAP;
    int j = 0;
    for (; j + 4 <= kc; j += 4) {
        int4 sv4 = *(const int4*)(sbase + j);
        float4 w4 = *(const float4*)(wbase + j);
        uint x0 = xpb[(size_t)sv4.x * 64 + lane];
        uint x1 = xpb[(size_t)sv4.y * 64 + lane];
        uint x2 = xpb[(size_t)sv4.z * 64 + lane];
        uint x3 = xpb[(size_t)sv4.w * 64 + lane];
        float2 f0 = bf2f(x0), f1 = bf2f(x1), f2 = bf2f(x2), f3 = bf2f(x3);
        acc0 += w4.x * f0.x + w4.y * f1.x + w4.z * f2.x + w4.w * f3.x;
        acc1 += w4.x * f0.y + w4.y * f1.y + w4.z * f2.y + w4.w * f3.y;
    }
    for (; j < kc; j++) {
        float w = wbase[j];
        int sv = sbase[j];
        float2 f = bf2f(xpb[(size_t)sv * 64 + lane]);
        acc0 += w * f.x; acc1 += w * f.y;
    }
    for (; j < k; j++) {                              // deg > CAP fallback (recompute)
        int4 r = *(const int4*)(ed + (size_t)(start + j) * 4);
        int sv = r.x;
        float a0 = __int_as_float(r.y), a1 = __int_as_float(r.z), a2 = __int_as_float(r.w);
        float wf = (j < k - 1) ? 1.f : loopw;
        float s = s_arr[sv * 4 + hh];
        float ev = a0 * mth.x + a1 * mth.y + a2 * mth.z + wf * mth.w;
        float a = s + dh + ev; a = a > 0.f ? a : 0.2f * a;
        float w = __expf(a);
        float2 f = bf2f(xpb[(size_t)sv * 64 + lane]);
        acc0 += w * f.x; acc1 += w * f.y;
    }
    *(float2*)(out + (size_t)node * 128 + lane * 2) = make_float2(acc0 * zi, acc1 * zi);
}

// BN stats: per-channel sum + sumsq  (gat_bias dropped: constant per channel, BN cancels it)
__global__ __launch_bounds__(256) void k_bnstats(const float* __restrict__ x, float* __restrict__ sums) {
    int tid = threadIdx.x;
    int c = tid & 127, half = tid >> 7;
    float s = 0.f, q = 0.f;
    for (int n = blockIdx.x * 2 + half; n < NN; n += gridDim.x * 2) {
        float v = x[n * 128 + c];
        s += v; q += v * v;
    }
    __shared__ float sh[256];
    sh[tid] = s; __syncthreads();
    if (tid < 128) atomicAdd(&sums[c], sh[tid] + sh[tid + 128]);
    __syncthreads();
    sh[tid] = q; __syncthreads();
    if (tid < 128) atomicAdd(&sums[128 + c], sh[tid] + sh[tid + 128]);
}

// BN + ReLU + residual; writes fp32 h and bf16-packed hb for next layer's MFMA GEMM
__global__ __launch_bounds__(256) void k_norm(const float* __restrict__ out, const float* __restrict__ sums,
                                              const float* __restrict__ gamma, const float* __restrict__ beta,
                                              float* __restrict__ h, uint* __restrict__ hb, int first) {
    int idx = blockIdx.x * 256 + threadIdx.x;
    if (idx >= NN * 64) return;
    int n = idx >> 6, c0 = (idx & 63) * 2;
    float2 v2 = *(const float2*)(out + (size_t)n * 128 + c0);
    float mu0 = sums[c0] * (1.f / NN), mu1 = sums[c0 + 1] * (1.f / NN);
    float var0 = sums[128 + c0] * (1.f / NN) - mu0 * mu0;
    float var1 = sums[128 + c0 + 1] * (1.f / NN) - mu1 * mu1;
    float iv0 = rsqrtf(fmaxf(var0, 0.f) + 1e-5f), iv1 = rsqrtf(fmaxf(var1, 0.f) + 1e-5f);
    float r0 = fmaxf((v2.x - mu0) * iv0 * gamma[c0] + beta[c0], 0.f);
    float r1 = fmaxf((v2.y - mu1) * iv1 * gamma[c0 + 1] + beta[c0 + 1], 0.f);
    if (!first) {
        float2 hp = *(const float2*)(h + (size_t)n * 128 + c0);
        r0 += hp.x; r1 += hp.y;
    }
    *(float2*)(h + (size_t)n * 128 + c0) = make_float2(r0, r1);
    hb[idx] = packbf(r0, r1);
}

// global mean pool: batch is SORTED -> one block per graph, binary-search range, no atomics
__global__ __launch_bounds__(128) void k_pool(const float* __restrict__ h, const int* __restrict__ batch,
                                              float* __restrict__ g) {
    int gi = blockIdx.x, t = threadIdx.x;
    int lo = 0, hi = NN;
    while (lo < hi) { int mid = (lo + hi) >> 1; if (batch[mid] < gi) lo = mid + 1; else hi = mid; }
    int start = lo;
    hi = NN;
    while (lo < hi) { int mid = (lo + hi) >> 1; if (batch[mid] < gi + 1) lo = mid + 1; else hi = mid; }
    int end = lo;
    float s = 0.f;
    for (int n = start; n < end; n++) s += h[(size_t)n * 128 + t];
    g[gi * 128 + t] = s / fmaxf((float)(end - start), 1.f);
}

__global__ __launch_bounds__(128) void k_fc(const float* __restrict__ g,
                                            const float* __restrict__ w1, const float* __restrict__ b1,
                                            const float* __restrict__ w2, const float* __restrict__ b2,
                                            const float* __restrict__ w3, const float* __restrict__ b3,
                                            float* __restrict__ out) {
    __shared__ float gv[128];
    __shared__ float h1[128];
    __shared__ float h2[64];
    int gi = blockIdx.x, t = threadIdx.x;
    gv[t] = g[gi * 128 + t];
    __syncthreads();
    float acc = b1[t];
    for (int kk = 0; kk < 128; kk++) acc += gv[kk] * w1[kk * 128 + t];
    h1[t] = fmaxf(acc, 0.f);
    __syncthreads();
    if (t < 64) {
        float a2 = b2[t];
        for (int kk = 0; kk < 128; kk++) a2 += h1[kk] * w2[kk * 64 + t];
        h2[t] = fmaxf(a2, 0.f);
    }
    __syncthreads();
    if (t < 64) {
        float p = h2[t] * w3[t];
#pragma unroll
        for (int off = 32; off; off >>= 1) p += __shfl_xor(p, off);
        if (t == 0) out[gi] = p + b3[0];
    }
}

extern "C" void kernel_launch(void* const* d_in, const int* in_sizes, int n_in,
                              void* d_out, int out_size, void* d_ws, size_t ws_size,
                              hipStream_t stream) {
    const float* x            = (const float*)d_in[0];
    const float* edge_attr    = (const float*)d_in[1];
    const int*   edge_index   = (const int*)d_in[2];
    const int*   batch        = (const int*)d_in[3];
    const float* enc_node_w   = (const float*)d_in[4];
    const float* enc_node_b   = (const float*)d_in[5];
    const float* enc_edge_w   = (const float*)d_in[6];
    const float* enc_edge_b   = (const float*)d_in[7];
    const float* gat_lin_w    = (const float*)d_in[8];
    const float* gat_att_src  = (const float*)d_in[9];
    const float* gat_att_dst  = (const float*)d_in[10];
    const float* gat_lin_edge = (const float*)d_in[11];
    const float* gat_att_edge = (const float*)d_in[12];
    // d_in[13] = gat_bias: constant per channel before training-mode BN -> cancels, unused
    const float* bn_gamma     = (const float*)d_in[14];
    const float* bn_beta      = (const float*)d_in[15];
    const float* fc1_w        = (const float*)d_in[16];
    const float* fc1_b        = (const float*)d_in[17];
    const float* fc2_w        = (const float*)d_in[18];
    const float* fc2_b        = (const float*)d_in[19];
    const float* fc3_w        = (const float*)d_in[20];
    const float* fc3_b        = (const float*)d_in[21];
    float* outv = (float*)d_out;

    char* ws = (char*)d_ws;
    size_t off = 0;
    auto alloc = [&](size_t bytes) -> void* {
        void* p = ws + off;
        off = (off + bytes + 255) & ~(size_t)255;
        return p;
    };
    float* h       = (float*)alloc((size_t)NN * 128 * 4);
    uint*  hbv     = (uint*)alloc((size_t)NN * 64 * 4);     // bf16-packed h
    float* gout    = (float*)alloc((size_t)NN * 128 * 4);
    uint*  xpb     = (uint*)alloc((size_t)NN * 64 * 4);     // bf16-packed xp
    float* s_arr   = (float*)alloc((size_t)NN * 4 * 4);
    float* d_arr   = (float*)alloc((size_t)NN * 4 * 4);
    int*   deg     = (int*)alloc((size_t)NN * 4);
    int*   fill    = (int*)alloc((size_t)NN * 4);
    int*   rp      = (int*)alloc((size_t)(NN + 1) * 4);
    int*   ed      = (int*)alloc((size_t)ET * 4 * 4);       // CSR records {src,a0,a1,a2}
    uint*  WbT     = (uint*)alloc((size_t)4 * 128 * 64 * 4);
    float* w_e     = (float*)alloc(128 * 16 * 4);
    float* Mt      = (float*)alloc(64 * 4);
    float* bns     = (float*)alloc(256 * 4);
    float* g       = (float*)alloc((size_t)GG * 128 * 4);
    (void)ws_size; (void)in_sizes; (void)n_in; (void)out_size;

    hipMemsetAsync(deg, 0, NN * 4, stream);

    const int* srce = edge_index;
    const int* dste = edge_index + EE;

    k_we<<<8, 256, 0, stream>>>(gat_lin_edge, gat_att_edge, w_e);
    k_me<<<1, 64, 0, stream>>>(enc_edge_w, enc_edge_b, w_e, Mt);
    k_wcvt<<<(4 * 128 * 64 + 255) / 256, 256, 0, stream>>>(gat_lin_w, WbT);
    k_enc<<<(NN * 64 + 255) / 256, 256, 0, stream>>>(x, enc_node_w, enc_node_b, h, hbv);
    k_deg<<<(EE / 4 + 255) / 256, 256, 0, stream>>>(dste, deg);
    k_scan<<<1, 1024, 0, stream>>>(deg, rp, fill);
    k_fill<<<(EE / 4 + 255) / 256, 256, 0, stream>>>(srce, dste, edge_attr, fill, ed);
    k_selfloop<<<(NN * 16 + 255) / 256, 256, 0, stream>>>(rp, ed);

    for (int l = 0; l < 4; l++) {
        k_gemm<<<(NN + 63) / 64, 256, 0, stream>>>(hbv, WbT + l * 8192,
                                                   gat_att_src + l * 128, gat_att_dst + l * 128,
                                                   xpb, s_arr, d_arr);
        k_edge<<<NN / 4, 256, 0, stream>>>(rp, ed, Mt, s_arr, d_arr, xpb, gout, l);
        hipMemsetAsync(bns, 0, 256 * 4, stream);
        k_bnstats<<<256, 256, 0, stream>>>(gout, bns);
        k_norm<<<(NN * 64 + 255) / 256, 256, 0, stream>>>(gout, bns, bn_gamma + l * 128,
                                                          bn_beta + l * 128, h, hbv, l == 0 ? 1 : 0);
    }

    k_pool<<<GG, 128, 0, stream>>>(h, batch, g);
    k_fc<<<GG, 128, 0, stream>>>(g, fc1_w, fc1_b, fc2_w, fc2_b, fc3_w, fc3_b, outv);
}